// Round 2
// baseline (1116.285 us; speedup 1.0000x reference)
//
#include <hip/hip_runtime.h>

typedef unsigned int u32;
typedef _Float16 f16;
typedef __attribute__((ext_vector_type(8))) _Float16 half8;
typedef __attribute__((ext_vector_type(4))) _Float16 half4;
typedef __attribute__((ext_vector_type(4))) float floatx4;

#define BAR() __builtin_amdgcn_s_barrier()
#define VM4() asm volatile("s_waitcnt vmcnt(4)" ::: "memory")
#define VM2() asm volatile("s_waitcnt vmcnt(2)" ::: "memory")
#define VM0() asm volatile("s_waitcnt vmcnt(0)" ::: "memory")
#define SETPRIO(x) __builtin_amdgcn_s_setprio(x)

// ------------- transpose + fp32->fp16: out[C][R] = (f16)in[R][C]^T -------
__global__ void transpose_w(const float* __restrict__ in, f16* __restrict__ out,
                            int R, int C) {
  __shared__ f16 t[32][33];
  const int bx = blockIdx.x * 32, by = blockIdx.y * 32;
  const int x = threadIdx.x, y0 = threadIdx.y;
  for (int y = y0; y < 32; y += 8)
    t[y][x] = (f16)in[(size_t)(by + y) * C + bx + x];
  __syncthreads();
  for (int y = y0; y < 32; y += 8)
    out[(size_t)(bx + y) * R + by + x] = t[x][y];
}

// ---------------- G1[b] = adj @ F[b]  (18x18 @ 18x1024), fp16 out -------
__global__ __launch_bounds__(256) void adjmix(const float* __restrict__ F,
                                              const float* __restrict__ adj,
                                              f16* __restrict__ G1) {
  __shared__ float adjs[324];
  for (int i = threadIdx.x; i < 324; i += 256) adjs[i] = adj[i];
  __syncthreads();
  const int d = blockIdx.x * 256 + threadIdx.x;
  const size_t base = (size_t)blockIdx.y * 18432;
  float f[18];
#pragma unroll
  for (int j = 0; j < 18; ++j) f[j] = F[base + j * 1024 + d];
#pragma unroll
  for (int i = 0; i < 18; ++i) {
    float a = 0.f;
#pragma unroll
    for (int j = 0; j < 18; ++j) a += adjs[i * 18 + j] * f[j];
    G1[base + i * 1024 + d] = (f16)a;
  }
}

// ---- C = A[M,K] @ Bt[N,K]^T, fp16 MFMA, 256x256 tile, BK=64, 8 waves.
// ---- m201-style 8-phase / 2-K-tile iteration: balanced ds_reads issued one
// ---- phase ahead of use, 2 global_load_lds per phase, counted vmcnt(2),
// ---- T2 XOR swizzle (0 conflicts), T5 setprio, T1 bijective XCD swizzle.
#define READ_A(DST, BUF, MB)                                             \
  {                                                                      \
    _Pragma("unroll") for (int m = 0; m < 4; ++m)                        \
        _Pragma("unroll") for (int s = 0; s < 2; ++s)                    \
            DST[m][s] = *(const half8*)(lds + (BUF)*32768 +              \
                ((abase + ((MB) + m) * 1024 + s * 32) ^ axor));          \
  }
#define READ_B(DST, BUF, NB)                                             \
  {                                                                      \
    _Pragma("unroll") for (int n = 0; n < 2; ++n)                        \
        _Pragma("unroll") for (int s = 0; s < 2; ++s)                    \
            DST[n][s] = *(const half8*)(lds + (BUF)*32768 + 16384 +      \
                ((bbase + ((NB) + n) * 1024 + s * 32) ^ axor));          \
  }
#define MFMA_Q(AA, BB, MO, NO)                                           \
  {                                                                      \
    SETPRIO(1);                                                          \
    _Pragma("unroll") for (int m = 0; m < 4; ++m)                        \
        _Pragma("unroll") for (int n = 0; n < 2; ++n)                    \
            _Pragma("unroll") for (int s = 0; s < 2; ++s) acc[(MO) + m]  \
                [(NO) + n] = __builtin_amdgcn_mfma_f32_16x16x32_f16(     \
                    AA[m][s], BB[n][s], acc[(MO) + m][(NO) + n], 0, 0,   \
                    0);                                                  \
    SETPRIO(0);                                                          \
  }

template <int MODE>
__global__ __launch_bounds__(512, 2) void gemm8(const f16* __restrict__ A,
                                                const f16* __restrict__ Bt,
                                                f16* __restrict__ C,
                                                int M, int N, int K) {
  // buf0: A @0, B @16384; buf1: A @32768, B @49152 (half units). 128 KiB.
  __shared__ __align__(16) f16 lds[65536];
  const int tid = threadIdx.x;
  const int wave = tid >> 6, lane = tid & 63;
  const int l16 = lane & 15, quad = lane >> 4;
  const int wr = wave >> 2, wc = wave & 3;  // 2M x 4N waves

  // ---- T1: bijective XCD swizzle; consecutive wg share the B panel ----
  const int MT = M >> 8;
  const int nwg = gridDim.x;
  const int orig = blockIdx.x;
  const int q = nwg >> 3, r = nwg & 7;
  const int xcd = orig & 7, idx = orig >> 3;
  const int wg = (xcd < r) ? xcd * (q + 1) + idx : r * (q + 1) + (xcd - r) * q + idx;
  const int mt = wg % MT, nt = wg / MT;
  const size_t m0 = (size_t)mt << 8, n0 = (size_t)nt << 8;

  // ---- staging: per-thread offset (g-independent), pre-swizzled source ----
  // LDS linear slot (row, cc) holds global chunk (row, cc ^ (row&7)).
  const int prow = tid >> 3;
  const int pcc = (tid & 7) ^ (prow & 7);
  const int poff = prow * K + pcc * 8;       // per-thread, same for A and B
  const int ldsb = (tid & ~63) * 8;          // wave-uniform dest base (halfs)
  const f16* Abase = A + m0 * (size_t)K;
  const f16* Bbase = Bt + n0 * (size_t)K;

  auto GLO = [&](const f16* gbase, int ldsoff) {
    __builtin_amdgcn_global_load_lds(
        (const __attribute__((address_space(1))) void*)(gbase + poff),
        (__attribute__((address_space(3))) void*)(lds + ldsoff + ldsb), 16, 0, 0);
  };
  // pair p of A-tile = rows p*128..p*128+127 (gloads 2p, 2p+1)
  auto STAGE_A = [&](int buf, int kk, int pair) {
#pragma unroll
    for (int g = 2 * pair; g < 2 * pair + 2; ++g)
      GLO(Abase + (size_t)(g * 64) * K + kk, buf * 32768 + g * 4096);
  };
  auto STAGE_B = [&](int buf, int kk, int pair) {
#pragma unroll
    for (int g = 2 * pair; g < 2 * pair + 2; ++g)
      GLO(Bbase + (size_t)(g * 64) * K + kk, buf * 32768 + 16384 + g * 4096);
  };

  // ---- T2: read-side swizzle constants (half units; XOR bits 3..5) ----
  const int axor = (l16 & 7) << 3;
  const int abase = (wr * 128 + l16) * 64 + quad * 8;
  const int bbase = (wc * 64 + l16) * 64 + quad * 8;

  floatx4 acc[8][4];
#pragma unroll
  for (int i = 0; i < 8; ++i)
#pragma unroll
    for (int j = 0; j < 4; ++j) acc[i][j] = (floatx4){0.f, 0.f, 0.f, 0.f};

  half8 aN[4][2], aF[4][2], bN[2][2], bF[2][2];

  const int KT2 = K >> 7;  // iterations; 2 K-tiles (t0=2i, t1=2i+1) each

  // ---- prologue: stage t0 A+B, t1 A; read aN,bN of t0; stage t1 B p0 ----
  STAGE_A(0, 0, 0);
  STAGE_A(0, 0, 1);
  STAGE_B(0, 0, 0);
  STAGE_B(0, 0, 1);
  STAGE_A(1, 64, 0);
  STAGE_A(1, 64, 1);
  VM4();  // t0 landed (t1 A in flight)
  BAR();
  READ_A(aN, 0, 0);
  READ_B(bN, 0, 0);
  STAGE_B(1, 64, 0);

#pragma unroll 1
  for (int i = 0; i < KT2; ++i) {
    const bool nx = (i + 1 < KT2);
    const int kt0 = i * 128;
    const int kt1 = kt0 + 64, kt2 = kt0 + 128, kt3 = kt0 + 192;

    // ph0: read aF[t0]; stage B[t1]p1; MFMA aN.bN[t0]
    READ_A(aF, 0, 4);
    STAGE_B(1, kt1, 1);
    BAR();
    MFMA_Q(aN, bN, 0, 0);
    BAR();

    // ph1: read bF[t0]; stage A[t2]p0; MFMA aF.bN[t0]
    READ_B(bF, 0, 2);
    if (nx) STAGE_A(0, kt2, 0);
    BAR();
    MFMA_Q(aF, bN, 4, 0);
    BAR();

    // ph2: vmcnt; read bN[t1]; stage A[t2]p1; MFMA aN.bF[t0]
    if (nx) VM2(); else VM0();
    READ_B(bN, 1, 0);
    if (nx) STAGE_A(0, kt2, 1);
    BAR();
    MFMA_Q(aN, bF, 0, 2);
    BAR();

    // ph3: read aN[t1]; stage B[t2]p0; MFMA aF.bF[t0]
    READ_A(aN, 1, 0);
    if (nx) STAGE_B(0, kt2, 0);
    BAR();
    MFMA_Q(aF, bF, 4, 2);
    BAR();

    // ph4: read aF[t1]; stage B[t2]p1; MFMA aN.bN[t1]
    READ_A(aF, 1, 4);
    if (nx) STAGE_B(0, kt2, 1);
    BAR();
    MFMA_Q(aN, bN, 0, 0);
    BAR();

    // ph5: read bF[t1]; stage A[t3]p0; MFMA aF.bN[t1]
    READ_B(bF, 1, 2);
    if (nx) STAGE_A(1, kt3, 0);
    BAR();
    MFMA_Q(aF, bN, 4, 0);
    BAR();

    // ph6: vmcnt(2); stage A[t3]p1; MFMA aN.bF[t1]; read aN[t2] (after use)
    if (nx) {
      VM2();
      STAGE_A(1, kt3, 1);
    }
    BAR();
    MFMA_Q(aN, bF, 0, 2);
    if (nx) READ_A(aN, 0, 0);
    BAR();

    // ph7: read bN[t2]; stage B[t3]p0; MFMA aF.bF[t1]
    if (nx) {
      READ_B(bN, 0, 0);
      STAGE_B(1, kt3, 0);
    }
    BAR();
    MFMA_Q(aF, bF, 4, 2);
    BAR();
  }

  // ---- epilogue: wave owns 128x64; C row = quad*4+reg, col = l16 ----
  const size_t cr0 = m0 + wr * 128 + quad * 4;
  const size_t cc0 = n0 + wc * 64 + l16;
#pragma unroll
  for (int m = 0; m < 8; ++m) {
    const size_t rb = cr0 + m * 16;
#pragma unroll
    for (int n = 0; n < 4; ++n) {
      const size_t cb = cc0 + n * 16;
#pragma unroll
      for (int rr = 0; rr < 4; ++rr) {
        float x = acc[m][n][rr];
        if (MODE == 0) x = x > 0.f ? x : 0.2f * x;
        C[(rb + rr) * N + cb] = (f16)x;
      }
    }
  }
}

// ---- fused attention core: T=F.H2^T (MFMA), softmax(T@adjT), An=P@F+F,
// ---- LN -> An (overwrites H2 buffer, block-local), row-mean -> Msh fp16.
#define HP2 1032
__global__ __launch_bounds__(256, 4) void fused_attn(
    const float* __restrict__ F, const float* __restrict__ adj,
    f16* __restrict__ H2,  // in: H2, out: An (same region, per-batch)
    const float* __restrict__ lnw, const float* __restrict__ lnb,
    f16* __restrict__ Msh) {
  __shared__ __align__(16) f16 Hs[18 * HP2];  // 36.3 KB: H2 tile
  __shared__ float Ts[18 * 20];               // T, then attn P (pitch 20)
  __shared__ float Red[324];                  // adj; later LN reduce scratch

  const int tid = threadIdx.x;
  const int lane = tid & 63, wave = tid >> 6;
  const int quad = lane >> 4, l16 = lane & 15;
  const int b = blockIdx.x;
  const float* Fb = F + (size_t)b * 18432;
  f16* Hb = H2 + (size_t)b * 18432;

  for (int i = tid; i < 2304; i += 256) {  // stage H2 (half8 coalesced)
    const int r = i >> 7, g = i & 127;
    *(half8*)(Hs + r * HP2 + g * 8) = *(const half8*)(Hb + r * 1024 + g * 8);
  }
  for (int i = tid; i < 324; i += 256) Red[i] = adj[i];
  __syncthreads();

  // T[m][n] = sum_k F[m,k]*H2[n,k] via MFMA; wave owns tile (mt,nt)
  {
    const int mt = wave >> 1, nt = wave & 1;
    const int arow = min(mt * 16 + l16, 17);
    const int brow = min(nt * 16 + l16, 17);
    const float* ap = Fb + arow * 1024 + quad * 8;
    const f16* bp = Hs + brow * HP2 + quad * 8;
    floatx4 acc = (floatx4){0.f, 0.f, 0.f, 0.f};
    for (int kc = 0; kc < 1024; kc += 32) {
      floatx4 a0 = *(const floatx4*)(ap + kc);
      floatx4 a1 = *(const floatx4*)(ap + kc + 4);
      half8 af;
      af[0] = (f16)a0[0]; af[1] = (f16)a0[1]; af[2] = (f16)a0[2]; af[3] = (f16)a0[3];
      af[4] = (f16)a1[0]; af[5] = (f16)a1[1]; af[6] = (f16)a1[2]; af[7] = (f16)a1[3];
      half8 bf = *(const half8*)(bp + kc);
      acc = __builtin_amdgcn_mfma_f32_16x16x32_f16(af, bf, acc, 0, 0, 0);
    }
    const int row = mt * 16 + quad * 4, col = nt * 16 + l16;
    if (col < 18) {
#pragma unroll
      for (int r = 0; r < 4; ++r)
        if (row + r < 18) Ts[(row + r) * 20 + col] = acc[r];
    }
  }
  __syncthreads();

  // S = T @ adj^T, row softmax -> P (in-place in Ts); lanes 0..17
  if (tid < 18) {
    float t[18], s[18];
#pragma unroll
    for (int j = 0; j < 18; ++j) t[j] = Ts[tid * 20 + j];
    float mx = -3.4e38f;
    for (int m = 0; m < 18; ++m) {
      float a = 0.f;
#pragma unroll
      for (int j = 0; j < 18; ++j) a += t[j] * Red[m * 18 + j];
      s[m] = a; mx = fmaxf(mx, a);
    }
    float sum = 0.f;
    for (int m = 0; m < 18; ++m) { s[m] = __expf(s[m] - mx); sum += s[m]; }
    const float inv = 1.f / sum;
    for (int m = 0; m < 18; ++m) Ts[tid * 20 + m] = s[m] * inv;
  }
  __syncthreads();

  // An = P@F + F, thread-per-column (cols d0+256k), fp32 F from global
  const int d0 = tid;
  floatx4 an[18];
#pragma unroll
  for (int i = 0; i < 18; ++i) an[i] = (floatx4){0.f, 0.f, 0.f, 0.f};
#pragma unroll
  for (int jb = 0; jb < 5; ++jb) {
    const int jn = (jb < 4) ? 4 : 2;
    floatx4 fj[4];
#pragma unroll
    for (int jj = 0; jj < 4; ++jj) {
      if (jj < jn) {
        const float* fp = Fb + (jb * 4 + jj) * 1024 + d0;
        fj[jj] = (floatx4){fp[0], fp[256], fp[512], fp[768]};
        an[jb * 4 + jj] += fj[jj];  // +F residual goes to row j
      }
    }
#pragma unroll
    for (int i = 0; i < 18; ++i) {
      floatx4 p4 = *(const floatx4*)(Ts + i * 20 + jb * 4);
#pragma unroll
      for (int jj = 0; jj < 4; ++jj)
        if (jj < jn) an[i] += p4[jj] * fj[jj];
    }
  }
  // stash An to Hs (fp16) + per-thread LN partials
  float s[18], ss[18];
#pragma unroll
  for (int i = 0; i < 18; ++i) {
    Hs[i * HP2 + d0] = (f16)an[i][0];
    Hs[i * HP2 + d0 + 256] = (f16)an[i][1];
    Hs[i * HP2 + d0 + 512] = (f16)an[i][2];
    Hs[i * HP2 + d0 + 768] = (f16)an[i][3];
    s[i] = an[i][0] + an[i][1] + an[i][2] + an[i][3];
    ss[i] = an[i][0] * an[i][0] + an[i][1] * an[i][1] +
            an[i][2] * an[i][2] + an[i][3] * an[i][3];
  }
#pragma unroll
  for (int i = 0; i < 18; ++i) {
#pragma unroll
    for (int off = 32; off > 0; off >>= 1) {
      s[i] += __shfl_xor(s[i], off);
      ss[i] += __shfl_xor(ss[i], off);
    }
  }
  if (lane == 0) {
#pragma unroll
    for (int i = 0; i < 18; ++i) {
      Red[wave * 36 + i] = s[i];
      Red[wave * 36 + 18 + i] = ss[i];
    }
  }
  __syncthreads();
  if (tid < 18) {
    const float sv = Red[tid] + Red[36 + tid] + Red[72 + tid] + Red[108 + tid];
    const float sq = Red[18 + tid] + Red[54 + tid] + Red[90 + tid] + Red[126 + tid];
    const float mu = sv * (1.f / 1024.f);
    Red[144 + tid] = mu;
    Red[162 + tid] = rsqrtf(sq * (1.f / 1024.f) - mu * mu + 1e-5f);
  }
  __syncthreads();

  // normalize, write An (=Hb) fp16 + Msh row-mean fp16
  const floatx4 wv = (floatx4){lnw[d0], lnw[d0 + 256], lnw[d0 + 512], lnw[d0 + 768]};
  const floatx4 bv = (floatx4){lnb[d0], lnb[d0 + 256], lnb[d0 + 512], lnb[d0 + 768]};
  floatx4 msum = (floatx4){0.f, 0.f, 0.f, 0.f};
#pragma unroll
  for (int i = 0; i < 18; ++i) {
    const float mu = Red[144 + i], rs = Red[162 + i];
    floatx4 v = (floatx4){(float)Hs[i * HP2 + d0], (float)Hs[i * HP2 + d0 + 256],
                          (float)Hs[i * HP2 + d0 + 512], (float)Hs[i * HP2 + d0 + 768]};
    floatx4 o;
#pragma unroll
    for (int k = 0; k < 4; ++k) o[k] = (v[k] - mu) * rs * wv[k] + bv[k];
    msum += o;
    Hb[i * 1024 + d0] = (f16)o[0];
    Hb[i * 1024 + d0 + 256] = (f16)o[1];
    Hb[i * 1024 + d0 + 512] = (f16)o[2];
    Hb[i * 1024 + d0 + 768] = (f16)o[3];
  }
  f16* mp = Msh + (size_t)b * 1024;
  mp[d0] = (f16)(msum[0] * (1.f / 18.f));
  mp[d0 + 256] = (f16)(msum[1] * (1.f / 18.f));
  mp[d0 + 512] = (f16)(msum[2] * (1.f / 18.f));
  mp[d0 + 768] = (f16)(msum[3] * (1.f / 18.f));
}

// ---- head GEMM: out[M x 14] = A[M x 1024](f16) @ W[14 x 1024]^T + bias ----
// grid.x = M/128; W staged fp16 in LDS; MFMA 16x16x32.
__global__ __launch_bounds__(256, 4) void head_gemm(
    const f16* __restrict__ A, const float* __restrict__ W,
    const float* __restrict__ bias, float* __restrict__ out) {
  __shared__ __align__(16) f16 Ws[14 * 1032];
  const int tid = threadIdx.x, lane = tid & 63, wave = tid >> 6;
  const int quad = lane >> 4, l16 = lane & 15;
  for (int i = tid; i < 3584; i += 256) {  // 14 rows x 256 float4 groups
    const int r = i >> 8, g = i & 255;
    floatx4 v = *(const floatx4*)(W + r * 1024 + g * 4);
    half4 h;
#pragma unroll
    for (int t = 0; t < 4; ++t) h[t] = (f16)v[t];
    *(half4*)(Ws + r * 1032 + g * 4) = h;
  }
  __syncthreads();
  const f16* bp = Ws + min(l16, 13) * 1032 + quad * 8;
  const float bia = (l16 < 14) ? bias[l16] : 0.f;
  const size_t mbase = (size_t)blockIdx.x * 128 + wave * 32;
#pragma unroll
  for (int mt = 0; mt < 2; ++mt) {
    const size_t m0 = mbase + mt * 16;
    const f16* apx = A + (m0 + l16) * 1024 + quad * 8;
    floatx4 acc = (floatx4){0.f, 0.f, 0.f, 0.f};
    for (int kc = 0; kc < 1024; kc += 32) {
      half8 af = *(const half8*)(apx + kc);
      half8 bf = *(const half8*)(bp + kc);
      acc = __builtin_amdgcn_mfma_f32_16x16x32_f16(af, bf, acc, 0, 0, 0);
    }
    if (l16 < 14) {
      const size_t row = m0 + quad * 4;
#pragma unroll
      for (int r = 0; r < 4; ++r) out[(row + r) * 14 + l16] = acc[r] + bia;
    }
  }
}

extern "C" void kernel_launch(void* const* d_in, const int* in_sizes, int n_in,
                              void* d_out, int out_size, void* d_ws, size_t ws_size,
                              hipStream_t stream) {
  const float* F    = (const float*)d_in[0];
  const float* adj  = (const float*)d_in[1];
  const float* w1   = (const float*)d_in[2];
  const float* w2   = (const float*)d_in[3];
  const float* lnw  = (const float*)d_in[4];
  const float* lnb  = (const float*)d_in[5];
  const float* fcnw = (const float*)d_in[6];
  const float* fcnb = (const float*)d_in[7];
  const float* fcgw = (const float*)d_in[8];
  const float* fcgb = (const float*)d_in[9];

  float* out_node  = (float*)d_out;
  float* out_graph = out_node + (size_t)2048 * 18 * 14;

  char* ws = (char*)d_ws;
  f16* W2t = (f16*)ws;                        // 4 MiB
  f16* W1t = (f16*)(ws + (size_t)(4 << 20));  // 4 MiB
  char* p8 = ws + (size_t)(8 << 20);

  transpose_w<<<dim3(64, 32), dim3(32, 8), 0, stream>>>(w1, W1t, 1024, 2048);
  transpose_w<<<dim3(32, 64), dim3(32, 8), 0, stream>>>(w2, W2t, 2048, 1024);

  const size_t G1_FULL = 75497472ull;   // 36864*1024*2
  const size_t X1_FULL = 150994944ull;  // 36864*2048*2
  const size_t NEED_A = (size_t)(8 << 20) + G1_FULL + X1_FULL;
  const size_t NEED_B = (size_t)(8 << 20) + G1_FULL + 9437184ull + 18874368ull + 4194304ull;

  if (ws_size >= NEED_A) {
    // Plan A: full batch. H2/An alias G1; Msh aliases X1 (dead after GEMM2).
    f16* G1 = (f16*)p8;
    f16* H2 = (f16*)p8;
    f16* X1 = (f16*)(p8 + G1_FULL);
    f16* Msh = (f16*)(p8 + G1_FULL);  // X1 region, reused after GEMM2
    adjmix<<<dim3(4, 2048), 256, 0, stream>>>(F, adj, G1);
    gemm8<0><<<dim3(1152), 512, 0, stream>>>(G1, W1t, X1, 36864, 2048, 1024);
    gemm8<1><<<dim3(576), 512, 0, stream>>>(X1, W2t, H2, 36864, 1024, 2048);
    fused_attn<<<2048, 256, 0, stream>>>(F, adj, H2, lnw, lnb, Msh);
    head_gemm<<<288, 256, 0, stream>>>(H2, fcnw, fcnb, out_node);
    head_gemm<<<16, 256, 0, stream>>>(Msh, fcgw, fcgb, out_graph);
  } else if (ws_size >= NEED_B) {
    // Plan B: chunked GEMMs, full H2/An + Msh.
    const int CH = 256, MC = CH * 18;
    f16* H2 = (f16*)p8;
    f16* G1c = (f16*)(p8 + G1_FULL);
    f16* X1c = (f16*)(p8 + G1_FULL + 9437184ull);
    f16* Msh = (f16*)(p8 + G1_FULL + 9437184ull + 18874368ull);
    for (int c = 0; c < 8; ++c) {
      const float* Fc = F + (size_t)c * CH * 18432;
      adjmix<<<dim3(4, CH), 256, 0, stream>>>(Fc, adj, G1c);
      gemm8<0><<<dim3(144), 512, 0, stream>>>(G1c, W1t, X1c, MC, 2048, 1024);
      gemm8<1><<<dim3(72), 512, 0, stream>>>(X1c, W2t,
                                             H2 + (size_t)c * MC * 1024,
                                             MC, 1024, 2048);
    }
    fused_attn<<<2048, 256, 0, stream>>>(F, adj, H2, lnw, lnb, Msh);
    head_gemm<<<288, 256, 0, stream>>>(H2, fcnw, fcnb, out_node);
    head_gemm<<<16, 256, 0, stream>>>(Msh, fcgw, fcgb, out_graph);
  } else {
    // Plan C: fully chunked (~46.7 MB floor).
    const int CH = 256, MC = CH * 18;
    f16* G1c = (f16*)p8;
    f16* X1c = (f16*)(p8 + 9437184ull);
    f16* H2c = (f16*)(p8 + 9437184ull + 18874368ull);
    f16* Mshc = (f16*)(p8 + 9437184ull + 18874368ull + 9437184ull);
    for (int c = 0; c < 8; ++c) {
      const float* Fc = F + (size_t)c * CH * 18432;
      adjmix<<<dim3(4, CH), 256, 0, stream>>>(Fc, adj, G1c);
      gemm8<0><<<dim3(144), 512, 0, stream>>>(G1c, W1t, X1c, MC, 2048, 1024);
      gemm8<1><<<dim3(72), 512, 0, stream>>>(X1c, W2t, H2c, MC, 1024, 2048);
      fused_attn<<<CH, 256, 0, stream>>>(Fc, adj, H2c, lnw, lnb, Mshc);
      head_gemm<<<36, 256, 0, stream>>>(H2c, fcnw, fcnb, out_node + (size_t)c * CH * 252);
      head_gemm<<<2, 256, 0, stream>>>(Mshc, fcgw, fcgb, out_graph + (size_t)c * CH * 14);
    }
  }
}

// Round 3
// 1113.559 us; speedup vs baseline: 1.0024x; 1.0024x over previous
//
#include <hip/hip_runtime.h>

typedef unsigned int u32;
typedef _Float16 f16;
typedef __attribute__((ext_vector_type(8))) _Float16 half8;
typedef __attribute__((ext_vector_type(4))) _Float16 half4;
typedef __attribute__((ext_vector_type(4))) float floatx4;

#define BAR() __builtin_amdgcn_s_barrier()
#define VM4() asm volatile("s_waitcnt vmcnt(4)" ::: "memory")
#define VM2() asm volatile("s_waitcnt vmcnt(2)" ::: "memory")
#define VM0() asm volatile("s_waitcnt vmcnt(0)" ::: "memory")
#define SETPRIO(x) __builtin_amdgcn_s_setprio(x)

// ------------- transpose + fp32->fp16: out[C][R] = (f16)in[R][C]^T -------
__global__ void transpose_w(const float* __restrict__ in, f16* __restrict__ out,
                            int R, int C) {
  __shared__ f16 t[32][33];
  const int bx = blockIdx.x * 32, by = blockIdx.y * 32;
  const int x = threadIdx.x, y0 = threadIdx.y;
  for (int y = y0; y < 32; y += 8)
    t[y][x] = (f16)in[(size_t)(by + y) * C + bx + x];
  __syncthreads();
  for (int y = y0; y < 32; y += 8)
    out[(size_t)(bx + y) * R + by + x] = t[x][y];
}

// ---------------- G1[b] = adj @ F[b]  (18x18 @ 18x1024), fp16 out -------
__global__ __launch_bounds__(256) void adjmix(const float* __restrict__ F,
                                              const float* __restrict__ adj,
                                              f16* __restrict__ G1) {
  __shared__ float adjs[324];
  for (int i = threadIdx.x; i < 324; i += 256) adjs[i] = adj[i];
  __syncthreads();
  const int d = blockIdx.x * 256 + threadIdx.x;
  const size_t base = (size_t)blockIdx.y * 18432;
  float f[18];
#pragma unroll
  for (int j = 0; j < 18; ++j) f[j] = F[base + j * 1024 + d];
#pragma unroll
  for (int i = 0; i < 18; ++i) {
    float a = 0.f;
#pragma unroll
    for (int j = 0; j < 18; ++j) a += adjs[i * 18 + j] * f[j];
    G1[base + i * 1024 + d] = (f16)a;
  }
}

// ---- C = A[M,K] @ Bt[N,K]^T, fp16 MFMA, 256x256 tile, BK=64, 8 waves.
// ---- m201-style 8-phase / 2-K-tile iteration: balanced ds_reads issued one
// ---- phase ahead of use, 2 global_load_lds per phase, counted vmcnt(2),
// ---- T2 XOR swizzle (0 conflicts), T5 setprio, T1 bijective XCD swizzle.
// ---- launch_bounds(512,1): LDS=128KiB forces 1 block/CU anyway; the
// ---- (512,2) variant capped VGPR at 128 and spilled ~170MB/dispatch.
#define READ_A(DST, BUF, MB)                                             \
  {                                                                      \
    _Pragma("unroll") for (int m = 0; m < 4; ++m)                        \
        _Pragma("unroll") for (int s = 0; s < 2; ++s)                    \
            DST[m][s] = *(const half8*)(lds + (BUF)*32768 +              \
                ((abase + ((MB) + m) * 1024 + s * 32) ^ axor));          \
  }
#define READ_B(DST, BUF, NB)                                             \
  {                                                                      \
    _Pragma("unroll") for (int n = 0; n < 2; ++n)                        \
        _Pragma("unroll") for (int s = 0; s < 2; ++s)                    \
            DST[n][s] = *(const half8*)(lds + (BUF)*32768 + 16384 +      \
                ((bbase + ((NB) + n) * 1024 + s * 32) ^ axor));          \
  }
#define MFMA_Q(AA, BB, MO, NO)                                           \
  {                                                                      \
    SETPRIO(1);                                                          \
    _Pragma("unroll") for (int m = 0; m < 4; ++m)                        \
        _Pragma("unroll") for (int n = 0; n < 2; ++n)                    \
            _Pragma("unroll") for (int s = 0; s < 2; ++s) acc[(MO) + m]  \
                [(NO) + n] = __builtin_amdgcn_mfma_f32_16x16x32_f16(     \
                    AA[m][s], BB[n][s], acc[(MO) + m][(NO) + n], 0, 0,   \
                    0);                                                  \
    SETPRIO(0);                                                          \
  }

template <int MODE>
__global__ __launch_bounds__(512, 1) void gemm8(const f16* __restrict__ A,
                                                const f16* __restrict__ Bt,
                                                f16* __restrict__ C,
                                                int M, int N, int K) {
  // buf0: A @0, B @16384; buf1: A @32768, B @49152 (half units). 128 KiB.
  __shared__ __align__(16) f16 lds[65536];
  const int tid = threadIdx.x;
  const int wave = tid >> 6, lane = tid & 63;
  const int l16 = lane & 15, quad = lane >> 4;
  const int wr = wave >> 2, wc = wave & 3;  // 2M x 4N waves

  // ---- T1: bijective XCD swizzle; consecutive wg share the B panel ----
  const int MT = M >> 8;
  const int nwg = gridDim.x;
  const int orig = blockIdx.x;
  const int q = nwg >> 3, r = nwg & 7;
  const int xcd = orig & 7, idx = orig >> 3;
  const int wg = (xcd < r) ? xcd * (q + 1) + idx : r * (q + 1) + (xcd - r) * q + idx;
  const int mt = wg % MT, nt = wg / MT;
  const size_t m0 = (size_t)mt << 8, n0 = (size_t)nt << 8;

  // ---- staging: per-thread offset (g-independent), pre-swizzled source ----
  // LDS linear slot (row, cc) holds global chunk (row, cc ^ (row&7)).
  const int prow = tid >> 3;
  const int pcc = (tid & 7) ^ (prow & 7);
  const int poff = prow * K + pcc * 8;       // per-thread, same for A and B
  const int ldsb = (tid & ~63) * 8;          // wave-uniform dest base (halfs)
  const f16* Abase = A + m0 * (size_t)K;
  const f16* Bbase = Bt + n0 * (size_t)K;

  auto GLO = [&](const f16* gbase, int ldsoff) {
    __builtin_amdgcn_global_load_lds(
        (const __attribute__((address_space(1))) void*)(gbase + poff),
        (__attribute__((address_space(3))) void*)(lds + ldsoff + ldsb), 16, 0, 0);
  };
  // pair p of A-tile = rows p*128..p*128+127 (gloads 2p, 2p+1)
  auto STAGE_A = [&](int buf, int kk, int pair) {
#pragma unroll
    for (int g = 2 * pair; g < 2 * pair + 2; ++g)
      GLO(Abase + (size_t)(g * 64) * K + kk, buf * 32768 + g * 4096);
  };
  auto STAGE_B = [&](int buf, int kk, int pair) {
#pragma unroll
    for (int g = 2 * pair; g < 2 * pair + 2; ++g)
      GLO(Bbase + (size_t)(g * 64) * K + kk, buf * 32768 + 16384 + g * 4096);
  };

  // ---- T2: read-side swizzle constants (half units; XOR bits 3..5) ----
  const int axor = (l16 & 7) << 3;
  const int abase = (wr * 128 + l16) * 64 + quad * 8;
  const int bbase = (wc * 64 + l16) * 64 + quad * 8;

  floatx4 acc[8][4];
#pragma unroll
  for (int i = 0; i < 8; ++i)
#pragma unroll
    for (int j = 0; j < 4; ++j) acc[i][j] = (floatx4){0.f, 0.f, 0.f, 0.f};

  half8 aN[4][2], aF[4][2], bN[2][2], bF[2][2];

  const int KT2 = K >> 7;  // iterations; 2 K-tiles (t0=2i, t1=2i+1) each

  // ---- prologue: stage t0 A+B, t1 A; read aN,bN of t0; stage t1 B p0 ----
  STAGE_A(0, 0, 0);
  STAGE_A(0, 0, 1);
  STAGE_B(0, 0, 0);
  STAGE_B(0, 0, 1);
  STAGE_A(1, 64, 0);
  STAGE_A(1, 64, 1);
  VM4();  // t0 landed (t1 A in flight)
  BAR();
  READ_A(aN, 0, 0);
  READ_B(bN, 0, 0);
  STAGE_B(1, 64, 0);

#pragma unroll 1
  for (int i = 0; i < KT2; ++i) {
    const bool nx = (i + 1 < KT2);
    const int kt0 = i * 128;
    const int kt1 = kt0 + 64, kt2 = kt0 + 128, kt3 = kt0 + 192;

    // ph0: read aF[t0]; stage B[t1]p1; MFMA aN.bN[t0]
    READ_A(aF, 0, 4);
    STAGE_B(1, kt1, 1);
    BAR();
    MFMA_Q(aN, bN, 0, 0);
    BAR();

    // ph1: read bF[t0]; stage A[t2]p0; MFMA aF.bN[t0]
    READ_B(bF, 0, 2);
    if (nx) STAGE_A(0, kt2, 0);
    BAR();
    MFMA_Q(aF, bN, 4, 0);
    BAR();

    // ph2: vmcnt; read bN[t1]; stage A[t2]p1; MFMA aN.bF[t0]
    if (nx) VM2(); else VM0();
    READ_B(bN, 1, 0);
    if (nx) STAGE_A(0, kt2, 1);
    BAR();
    MFMA_Q(aN, bF, 0, 2);
    BAR();

    // ph3: read aN[t1]; stage B[t2]p0; MFMA aF.bF[t0]
    READ_A(aN, 1, 0);
    if (nx) STAGE_B(0, kt2, 0);
    BAR();
    MFMA_Q(aF, bF, 4, 2);
    BAR();

    // ph4: read aF[t1]; stage B[t2]p1; MFMA aN.bN[t1]
    READ_A(aF, 1, 4);
    if (nx) STAGE_B(0, kt2, 1);
    BAR();
    MFMA_Q(aN, bN, 0, 0);
    BAR();

    // ph5: read bF[t1]; stage A[t3]p0; MFMA aF.bN[t1]
    READ_B(bF, 1, 2);
    if (nx) STAGE_A(1, kt3, 0);
    BAR();
    MFMA_Q(aF, bN, 4, 0);
    BAR();

    // ph6: vmcnt(2); stage A[t3]p1; MFMA aN.bF[t1]; read aN[t2] (after use)
    if (nx) {
      VM2();
      STAGE_A(1, kt3, 1);
    }
    BAR();
    MFMA_Q(aN, bF, 0, 2);
    if (nx) READ_A(aN, 0, 0);
    BAR();

    // ph7: read bN[t2]; stage B[t3]p0; MFMA aF.bF[t1]
    if (nx) {
      READ_B(bN, 0, 0);
      STAGE_B(1, kt3, 0);
    }
    BAR();
    MFMA_Q(aF, bF, 4, 2);
    BAR();
  }

  // ---- epilogue: wave owns 128x64; C row = quad*4+reg, col = l16 ----
  const size_t cr0 = m0 + wr * 128 + quad * 4;
  const size_t cc0 = n0 + wc * 64 + l16;
#pragma unroll
  for (int m = 0; m < 8; ++m) {
    const size_t rb = cr0 + m * 16;
#pragma unroll
    for (int n = 0; n < 4; ++n) {
      const size_t cb = cc0 + n * 16;
#pragma unroll
      for (int rr = 0; rr < 4; ++rr) {
        float x = acc[m][n][rr];
        if (MODE == 0) x = x > 0.f ? x : 0.2f * x;
        C[(rb + rr) * N + cb] = (f16)x;
      }
    }
  }
}

// ---- fused attention core: T=F.H2^T (MFMA), softmax(T@adjT), An=P@F+F,
// ---- LN -> An (overwrites H2 buffer, block-local), row-mean -> Msh fp16.
#define HP2 1032
__global__ __launch_bounds__(256, 4) void fused_attn(
    const float* __restrict__ F, const float* __restrict__ adj,
    f16* __restrict__ H2,  // in: H2, out: An (same region, per-batch)
    const float* __restrict__ lnw, const float* __restrict__ lnb,
    f16* __restrict__ Msh) {
  __shared__ __align__(16) f16 Hs[18 * HP2];  // 36.3 KB: H2 tile
  __shared__ float Ts[18 * 20];               // T, then attn P (pitch 20)
  __shared__ float Red[324];                  // adj; later LN reduce scratch

  const int tid = threadIdx.x;
  const int lane = tid & 63, wave = tid >> 6;
  const int quad = lane >> 4, l16 = lane & 15;
  const int b = blockIdx.x;
  const float* Fb = F + (size_t)b * 18432;
  f16* Hb = H2 + (size_t)b * 18432;

  for (int i = tid; i < 2304; i += 256) {  // stage H2 (half8 coalesced)
    const int r = i >> 7, g = i & 127;
    *(half8*)(Hs + r * HP2 + g * 8) = *(const half8*)(Hb + r * 1024 + g * 8);
  }
  for (int i = tid; i < 324; i += 256) Red[i] = adj[i];
  __syncthreads();

  // T[m][n] = sum_k F[m,k]*H2[n,k] via MFMA; wave owns tile (mt,nt)
  {
    const int mt = wave >> 1, nt = wave & 1;
    const int arow = min(mt * 16 + l16, 17);
    const int brow = min(nt * 16 + l16, 17);
    const float* ap = Fb + arow * 1024 + quad * 8;
    const f16* bp = Hs + brow * HP2 + quad * 8;
    floatx4 acc = (floatx4){0.f, 0.f, 0.f, 0.f};
    for (int kc = 0; kc < 1024; kc += 32) {
      floatx4 a0 = *(const floatx4*)(ap + kc);
      floatx4 a1 = *(const floatx4*)(ap + kc + 4);
      half8 af;
      af[0] = (f16)a0[0]; af[1] = (f16)a0[1]; af[2] = (f16)a0[2]; af[3] = (f16)a0[3];
      af[4] = (f16)a1[0]; af[5] = (f16)a1[1]; af[6] = (f16)a1[2]; af[7] = (f16)a1[3];
      half8 bf = *(const half8*)(bp + kc);
      acc = __builtin_amdgcn_mfma_f32_16x16x32_f16(af, bf, acc, 0, 0, 0);
    }
    const int row = mt * 16 + quad * 4, col = nt * 16 + l16;
    if (col < 18) {
#pragma unroll
      for (int r = 0; r < 4; ++r)
        if (row + r < 18) Ts[(row + r) * 20 + col] = acc[r];
    }
  }
  __syncthreads();

  // S = T @ adj^T, row softmax -> P (in-place in Ts); lanes 0..17
  if (tid < 18) {
    float t[18], s[18];
#pragma unroll
    for (int j = 0; j < 18; ++j) t[j] = Ts[tid * 20 + j];
    float mx = -3.4e38f;
    for (int m = 0; m < 18; ++m) {
      float a = 0.f;
#pragma unroll
      for (int j = 0; j < 18; ++j) a += t[j] * Red[m * 18 + j];
      s[m] = a; mx = fmaxf(mx, a);
    }
    float sum = 0.f;
    for (int m = 0; m < 18; ++m) { s[m] = __expf(s[m] - mx); sum += s[m]; }
    const float inv = 1.f / sum;
    for (int m = 0; m < 18; ++m) Ts[tid * 20 + m] = s[m] * inv;
  }
  __syncthreads();

  // An = P@F + F, thread-per-column (cols d0+256k), fp32 F from global
  const int d0 = tid;
  floatx4 an[18];
#pragma unroll
  for (int i = 0; i < 18; ++i) an[i] = (floatx4){0.f, 0.f, 0.f, 0.f};
#pragma unroll
  for (int jb = 0; jb < 5; ++jb) {
    const int jn = (jb < 4) ? 4 : 2;
    floatx4 fj[4];
#pragma unroll
    for (int jj = 0; jj < 4; ++jj) {
      if (jj < jn) {
        const float* fp = Fb + (jb * 4 + jj) * 1024 + d0;
        fj[jj] = (floatx4){fp[0], fp[256], fp[512], fp[768]};
        an[jb * 4 + jj] += fj[jj];  // +F residual goes to row j
      }
    }
#pragma unroll
    for (int i = 0; i < 18; ++i) {
      floatx4 p4 = *(const floatx4*)(Ts + i * 20 + jb * 4);
#pragma unroll
      for (int jj = 0; jj < 4; ++jj)
        if (jj < jn) an[i] += p4[jj] * fj[jj];
    }
  }
  // stash An to Hs (fp16) + per-thread LN partials
  float s[18], ss[18];
#pragma unroll
  for (int i = 0; i < 18; ++i) {
    Hs[i * HP2 + d0] = (f16)an[i][0];
    Hs[i * HP2 + d0 + 256] = (f16)an[i][1];
    Hs[i * HP2 + d0 + 512] = (f16)an[i][2];
    Hs[i * HP2 + d0 + 768] = (f16)an[i][3];
    s[i] = an[i][0] + an[i][1] + an[i][2] + an[i][3];
    ss[i] = an[i][0] * an[i][0] + an[i][1] * an[i][1] +
            an[i][2] * an[i][2] + an[i][3] * an[i][3];
  }
#pragma unroll
  for (int i = 0; i < 18; ++i) {
#pragma unroll
    for (int off = 32; off > 0; off >>= 1) {
      s[i] += __shfl_xor(s[i], off);
      ss[i] += __shfl_xor(ss[i], off);
    }
  }
  if (lane == 0) {
#pragma unroll
    for (int i = 0; i < 18; ++i) {
      Red[wave * 36 + i] = s[i];
      Red[wave * 36 + 18 + i] = ss[i];
    }
  }
  __syncthreads();
  if (tid < 18) {
    const float sv = Red[tid] + Red[36 + tid] + Red[72 + tid] + Red[108 + tid];
    const float sq = Red[18 + tid] + Red[54 + tid] + Red[90 + tid] + Red[126 + tid];
    const float mu = sv * (1.f / 1024.f);
    Red[144 + tid] = mu;
    Red[162 + tid] = rsqrtf(sq * (1.f / 1024.f) - mu * mu + 1e-5f);
  }
  __syncthreads();

  // normalize, write An (=Hb) fp16 + Msh row-mean fp16
  const floatx4 wv = (floatx4){lnw[d0], lnw[d0 + 256], lnw[d0 + 512], lnw[d0 + 768]};
  const floatx4 bv = (floatx4){lnb[d0], lnb[d0 + 256], lnb[d0 + 512], lnb[d0 + 768]};
  floatx4 msum = (floatx4){0.f, 0.f, 0.f, 0.f};
#pragma unroll
  for (int i = 0; i < 18; ++i) {
    const float mu = Red[144 + i], rs = Red[162 + i];
    floatx4 v = (floatx4){(float)Hs[i * HP2 + d0], (float)Hs[i * HP2 + d0 + 256],
                          (float)Hs[i * HP2 + d0 + 512], (float)Hs[i * HP2 + d0 + 768]};
    floatx4 o;
#pragma unroll
    for (int k = 0; k < 4; ++k) o[k] = (v[k] - mu) * rs * wv[k] + bv[k];
    msum += o;
    Hb[i * 1024 + d0] = (f16)o[0];
    Hb[i * 1024 + d0 + 256] = (f16)o[1];
    Hb[i * 1024 + d0 + 512] = (f16)o[2];
    Hb[i * 1024 + d0 + 768] = (f16)o[3];
  }
  f16* mp = Msh + (size_t)b * 1024;
  mp[d0] = (f16)(msum[0] * (1.f / 18.f));
  mp[d0 + 256] = (f16)(msum[1] * (1.f / 18.f));
  mp[d0 + 512] = (f16)(msum[2] * (1.f / 18.f));
  mp[d0 + 768] = (f16)(msum[3] * (1.f / 18.f));
}

// ---- head GEMM: out[M x 14] = A[M x 1024](f16) @ W[14 x 1024]^T + bias ----
// grid.x = M/128; W staged fp16 in LDS; MFMA 16x16x32.
__global__ __launch_bounds__(256, 4) void head_gemm(
    const f16* __restrict__ A, const float* __restrict__ W,
    const float* __restrict__ bias, float* __restrict__ out) {
  __shared__ __align__(16) f16 Ws[14 * 1032];
  const int tid = threadIdx.x, lane = tid & 63, wave = tid >> 6;
  const int quad = lane >> 4, l16 = lane & 15;
  for (int i = tid; i < 3584; i += 256) {  // 14 rows x 256 float4 groups
    const int r = i >> 8, g = i & 255;
    floatx4 v = *(const floatx4*)(W + r * 1024 + g * 4);
    half4 h;
#pragma unroll
    for (int t = 0; t < 4; ++t) h[t] = (f16)v[t];
    *(half4*)(Ws + r * 1032 + g * 4) = h;
  }
  __syncthreads();
  const f16* bp = Ws + min(l16, 13) * 1032 + quad * 8;
  const float bia = (l16 < 14) ? bias[l16] : 0.f;
  const size_t mbase = (size_t)blockIdx.x * 128 + wave * 32;
#pragma unroll
  for (int mt = 0; mt < 2; ++mt) {
    const size_t m0 = mbase + mt * 16;
    const f16* apx = A + (m0 + l16) * 1024 + quad * 8;
    floatx4 acc = (floatx4){0.f, 0.f, 0.f, 0.f};
    for (int kc = 0; kc < 1024; kc += 32) {
      half8 af = *(const half8*)(apx + kc);
      half8 bf = *(const half8*)(bp + kc);
      acc = __builtin_amdgcn_mfma_f32_16x16x32_f16(af, bf, acc, 0, 0, 0);
    }
    if (l16 < 14) {
      const size_t row = m0 + quad * 4;
#pragma unroll
      for (int r = 0; r < 4; ++r) out[(row + r) * 14 + l16] = acc[r] + bia;
    }
  }
}

extern "C" void kernel_launch(void* const* d_in, const int* in_sizes, int n_in,
                              void* d_out, int out_size, void* d_ws, size_t ws_size,
                              hipStream_t stream) {
  const float* F    = (const float*)d_in[0];
  const float* adj  = (const float*)d_in[1];
  const float* w1   = (const float*)d_in[2];
  const float* w2   = (const float*)d_in[3];
  const float* lnw  = (const float*)d_in[4];
  const float* lnb  = (const float*)d_in[5];
  const float* fcnw = (const float*)d_in[6];
  const float* fcnb = (const float*)d_in[7];
  const float* fcgw = (const float*)d_in[8];
  const float* fcgb = (const float*)d_in[9];

  float* out_node  = (float*)d_out;
  float* out_graph = out_node + (size_t)2048 * 18 * 14;

  char* ws = (char*)d_ws;
  f16* W2t = (f16*)ws;                        // 4 MiB
  f16* W1t = (f16*)(ws + (size_t)(4 << 20));  // 4 MiB
  char* p8 = ws + (size_t)(8 << 20);

  transpose_w<<<dim3(64, 32), dim3(32, 8), 0, stream>>>(w1, W1t, 1024, 2048);
  transpose_w<<<dim3(32, 64), dim3(32, 8), 0, stream>>>(w2, W2t, 2048, 1024);

  const size_t G1_FULL = 75497472ull;   // 36864*1024*2
  const size_t X1_FULL = 150994944ull;  // 36864*2048*2
  const size_t NEED_A = (size_t)(8 << 20) + G1_FULL + X1_FULL;
  const size_t NEED_B = (size_t)(8 << 20) + G1_FULL + 9437184ull + 18874368ull + 4194304ull;

  if (ws_size >= NEED_A) {
    // Plan A: full batch. H2/An alias G1; Msh aliases X1 (dead after GEMM2).
    f16* G1 = (f16*)p8;
    f16* H2 = (f16*)p8;
    f16* X1 = (f16*)(p8 + G1_FULL);
    f16* Msh = (f16*)(p8 + G1_FULL);  // X1 region, reused after GEMM2
    adjmix<<<dim3(4, 2048), 256, 0, stream>>>(F, adj, G1);
    gemm8<0><<<dim3(1152), 512, 0, stream>>>(G1, W1t, X1, 36864, 2048, 1024);
    gemm8<1><<<dim3(576), 512, 0, stream>>>(X1, W2t, H2, 36864, 1024, 2048);
    fused_attn<<<2048, 256, 0, stream>>>(F, adj, H2, lnw, lnb, Msh);
    head_gemm<<<288, 256, 0, stream>>>(H2, fcnw, fcnb, out_node);
    head_gemm<<<16, 256, 0, stream>>>(Msh, fcgw, fcgb, out_graph);
  } else if (ws_size >= NEED_B) {
    // Plan B: chunked GEMMs, full H2/An + Msh.
    const int CH = 256, MC = CH * 18;
    f16* H2 = (f16*)p8;
    f16* G1c = (f16*)(p8 + G1_FULL);
    f16* X1c = (f16*)(p8 + G1_FULL + 9437184ull);
    f16* Msh = (f16*)(p8 + G1_FULL + 9437184ull + 18874368ull);
    for (int c = 0; c < 8; ++c) {
      const float* Fc = F + (size_t)c * CH * 18432;
      adjmix<<<dim3(4, CH), 256, 0, stream>>>(Fc, adj, G1c);
      gemm8<0><<<dim3(144), 512, 0, stream>>>(G1c, W1t, X1c, MC, 2048, 1024);
      gemm8<1><<<dim3(72), 512, 0, stream>>>(X1c, W2t,
                                             H2 + (size_t)c * MC * 1024,
                                             MC, 1024, 2048);
    }
    fused_attn<<<2048, 256, 0, stream>>>(F, adj, H2, lnw, lnb, Msh);
    head_gemm<<<288, 256, 0, stream>>>(H2, fcnw, fcnb, out_node);
    head_gemm<<<16, 256, 0, stream>>>(Msh, fcgw, fcgb, out_graph);
  } else {
    // Plan C: fully chunked (~46.7 MB floor).
    const int CH = 256, MC = CH * 18;
    f16* G1c = (f16*)p8;
    f16* X1c = (f16*)(p8 + 9437184ull);
    f16* H2c = (f16*)(p8 + 9437184ull + 18874368ull);
    f16* Mshc = (f16*)(p8 + 9437184ull + 18874368ull + 9437184ull);
    for (int c = 0; c < 8; ++c) {
      const float* Fc = F + (size_t)c * CH * 18432;
      adjmix<<<dim3(4, CH), 256, 0, stream>>>(Fc, adj, G1c);
      gemm8<0><<<dim3(144), 512, 0, stream>>>(G1c, W1t, X1c, MC, 2048, 1024);
      gemm8<1><<<dim3(72), 512, 0, stream>>>(X1c, W2t, H2c, MC, 1024, 2048);
      fused_attn<<<CH, 256, 0, stream>>>(Fc, adj, H2c, lnw, lnb, Mshc);
      head_gemm<<<36, 256, 0, stream>>>(H2c, fcnw, fcnb, out_node + (size_t)c * CH * 252);
      head_gemm<<<2, 256, 0, stream>>>(Mshc, fcgw, fcgb, out_graph + (size_t)c * CH * 14);
    }
  }
}

// Round 6
// 769.933 us; speedup vs baseline: 1.4498x; 1.4463x over previous
//
#include <hip/hip_runtime.h>

typedef unsigned int u32;
typedef _Float16 f16;
typedef __attribute__((ext_vector_type(8))) _Float16 half8;
typedef __attribute__((ext_vector_type(4))) _Float16 half4;
typedef __attribute__((ext_vector_type(4))) float floatx4;

#define BAR() __builtin_amdgcn_s_barrier()
#define LGKM0() asm volatile("s_waitcnt lgkmcnt(0)" ::: "memory")
#define VM8() asm volatile("s_waitcnt vmcnt(8)" ::: "memory")
#define VM0() asm volatile("s_waitcnt vmcnt(0)" ::: "memory")
#define SETPRIO(x) __builtin_amdgcn_s_setprio(x)

// ------------- transpose + fp32->fp16: out[C][R] = (f16)in[R][C]^T -------
__global__ void transpose_w(const float* __restrict__ in, f16* __restrict__ out,
                            int R, int C) {
  __shared__ f16 t[32][33];
  const int bx = blockIdx.x * 32, by = blockIdx.y * 32;
  const int x = threadIdx.x, y0 = threadIdx.y;
  for (int y = y0; y < 32; y += 8)
    t[y][x] = (f16)in[(size_t)(by + y) * C + bx + x];
  __syncthreads();
  for (int y = y0; y < 32; y += 8)
    out[(size_t)(bx + y) * R + by + x] = t[x][y];
}

// ---- G1[b] = adj @ F[b] (18x18 @ 18x1024), fp16 out. One block/batch, ----
// ---- float4 loads + half4 stores (G13: vectorize memory-bound kernels). ----
__global__ __launch_bounds__(256) void adjmix(const float* __restrict__ F,
                                              const float* __restrict__ adj,
                                              f16* __restrict__ G1) {
  __shared__ float adjs[324];
  for (int i = threadIdx.x; i < 324; i += 256) adjs[i] = adj[i];
  __syncthreads();
  const int d = threadIdx.x * 4;
  const size_t base = (size_t)blockIdx.x * 18432;
  floatx4 f[18];
#pragma unroll
  for (int j = 0; j < 18; ++j)
    f[j] = *(const floatx4*)(F + base + j * 1024 + d);
#pragma unroll
  for (int i = 0; i < 18; ++i) {
    floatx4 a = (floatx4){0.f, 0.f, 0.f, 0.f};
#pragma unroll
    for (int j = 0; j < 18; ++j) a += adjs[i * 18 + j] * f[j];
    half4 h;
#pragma unroll
    for (int k = 0; k < 4; ++k) h[k] = (f16)a[k];
    *(half4*)(G1 + base + i * 1024 + d) = h;
  }
}

// ---- C = A[M,K] @ Bt[N,K]^T, fp16 MFMA, 256x256 tile, BK=64, 8 waves. ----
// ---- EXACT Round-1 schedule (hardware-verified correct, 770us): per-phase
// ---- ds_reads, ALL 8 global_load_lds clumped in ph3, VM8 counted wait.
// ---- Spread-staging variants (R3/R4) failed correctness twice -> banned.
template <int MODE>
__global__ __launch_bounds__(512, 2) void gemm8(const f16* __restrict__ A,
                                                const f16* __restrict__ Bt,
                                                f16* __restrict__ C,
                                                int M, int N, int K) {
  // buf0: A @0, B @16384; buf1: A @32768, B @49152 (half units). 128 KiB.
  __shared__ __align__(16) f16 lds[65536];
  const int tid = threadIdx.x;
  const int wave = tid >> 6, lane = tid & 63;
  const int l16 = lane & 15, quad = lane >> 4;
  const int wr = wave >> 2, wc = wave & 3;  // 2M x 4N waves

  // ---- T1: bijective XCD swizzle; consecutive wg share the B panel ----
  const int MT = M >> 8;
  const int nwg = gridDim.x;
  const int orig = blockIdx.x;
  const int q = nwg >> 3, r = nwg & 7;
  const int xcd = orig & 7, idx = orig >> 3;
  const int wg = (xcd < r) ? xcd * (q + 1) + idx : r * (q + 1) + (xcd - r) * q + idx;
  const int mt = wg % MT, nt = wg / MT;
  const size_t m0 = (size_t)mt << 8, n0 = (size_t)nt << 8;

  // ---- staging source pointers (pre-swizzled global chunk, rule 21) ----
  // LDS linear slot (row, cc) holds global chunk (row, cc ^ (row&7)).
  const f16* gA[4];
  const f16* gB[4];
  int ldso[4];
#pragma unroll
  for (int g = 0; g < 4; ++g) {
    const int c = g * 512 + tid;
    const int row = c >> 3;
    const int cc = (c & 7) ^ (row & 7);
    gA[g] = A + (m0 + row) * (size_t)K + cc * 8;
    gB[g] = Bt + (n0 + row) * (size_t)K + cc * 8;
    ldso[g] = (g * 512 + (tid & ~63)) * 8;  // wave-uniform dest base (halfs)
  }

  auto STAGE = [&](int buf, int kk) {
    f16* lA = lds + buf * 32768;
    f16* lB = lA + 16384;
#pragma unroll
    for (int g = 0; g < 4; ++g)
      __builtin_amdgcn_global_load_lds(
          (const __attribute__((address_space(1))) void*)(gA[g] + kk),
          (__attribute__((address_space(3))) void*)(lA + ldso[g]), 16, 0, 0);
#pragma unroll
    for (int g = 0; g < 4; ++g)
      __builtin_amdgcn_global_load_lds(
          (const __attribute__((address_space(1))) void*)(gB[g] + kk),
          (__attribute__((address_space(3))) void*)(lB + ldso[g]), 16, 0, 0);
  };

  // ---- T2: read-side swizzle constants (half units; XOR bits 3..5) ----
  const int axor = (l16 & 7) << 3;
  const int abase = (wr * 128 + l16) * 64 + quad * 8;
  const int bbase = (wc * 64 + l16) * 64 + quad * 8;

  floatx4 acc[8][4];
#pragma unroll
  for (int i = 0; i < 8; ++i)
#pragma unroll
    for (int j = 0; j < 4; ++j) acc[i][j] = (floatx4){0.f, 0.f, 0.f, 0.f};

  const int KT = K >> 6;
  STAGE(0, 0);
  STAGE(1, 64);
  VM8();  // tile0 landed (tile1's 8 loads may fly)
  BAR();

#pragma unroll 1
  for (int T = 0; T < KT; ++T) {
    f16* lA = lds + (T & 1) * 32768;
    f16* lB = lA + 16384;
    const bool st = (T + 2 < KT);
    half8 aF[4][2], bL[2][2], bH[2][2];

    // ---- phase 0: ds_read A[0..3] + B[0..1]; MFMA (lo,lo) ----
#pragma unroll
    for (int m = 0; m < 4; ++m)
#pragma unroll
      for (int s = 0; s < 2; ++s)
        aF[m][s] = *(const half8*)(lA + ((abase + m * 1024 + s * 32) ^ axor));
#pragma unroll
    for (int n = 0; n < 2; ++n)
#pragma unroll
      for (int s = 0; s < 2; ++s)
        bL[n][s] = *(const half8*)(lB + ((bbase + n * 1024 + s * 32) ^ axor));
    BAR();
    LGKM0();
    SETPRIO(1);
#pragma unroll
    for (int m = 0; m < 4; ++m)
#pragma unroll
      for (int n = 0; n < 2; ++n)
#pragma unroll
        for (int s = 0; s < 2; ++s)
          acc[m][n] = __builtin_amdgcn_mfma_f32_16x16x32_f16(aF[m][s], bL[n][s], acc[m][n], 0, 0, 0);
    SETPRIO(0);
    BAR();

    // ---- phase 1: ds_read B[2..3]; MFMA (lo,hi) ----
#pragma unroll
    for (int n = 0; n < 2; ++n)
#pragma unroll
      for (int s = 0; s < 2; ++s)
        bH[n][s] = *(const half8*)(lB + ((bbase + (n + 2) * 1024 + s * 32) ^ axor));
    BAR();
    LGKM0();
    SETPRIO(1);
#pragma unroll
    for (int m = 0; m < 4; ++m)
#pragma unroll
      for (int n = 0; n < 2; ++n)
#pragma unroll
        for (int s = 0; s < 2; ++s)
          acc[m][2 + n] = __builtin_amdgcn_mfma_f32_16x16x32_f16(aF[m][s], bH[n][s], acc[m][2 + n], 0, 0, 0);
    SETPRIO(0);
    BAR();

    // ---- phase 2: ds_read A[4..7]; MFMA (hi,lo) ----
#pragma unroll
    for (int m = 0; m < 4; ++m)
#pragma unroll
      for (int s = 0; s < 2; ++s)
        aF[m][s] = *(const half8*)(lA + ((abase + (m + 4) * 1024 + s * 32) ^ axor));
    BAR();
    LGKM0();
    SETPRIO(1);
#pragma unroll
    for (int m = 0; m < 4; ++m)
#pragma unroll
      for (int n = 0; n < 2; ++n)
#pragma unroll
        for (int s = 0; s < 2; ++s)
          acc[4 + m][n] = __builtin_amdgcn_mfma_f32_16x16x32_f16(aF[m][s], bL[n][s], acc[4 + m][n], 0, 0, 0);
    SETPRIO(0);
    BAR();

    // ---- phase 3: stage tile T+2 into this buf (reads done); MFMA (hi,hi);
    // ---- counted vmcnt (T4): never 0 in steady state ----
    if (st) STAGE(T & 1, (T + 2) * 64);
    BAR();
    SETPRIO(1);
#pragma unroll
    for (int m = 0; m < 4; ++m)
#pragma unroll
      for (int n = 0; n < 2; ++n)
#pragma unroll
        for (int s = 0; s < 2; ++s)
          acc[4 + m][2 + n] = __builtin_amdgcn_mfma_f32_16x16x32_f16(aF[m][s], bH[n][s], acc[4 + m][2 + n], 0, 0, 0);
    SETPRIO(0);
    if (st) {
      VM8();  // tile T+1 landed; tile T+2's 8 loads stay in flight
    } else if (T + 1 < KT) {
      VM0();  // drain tail: ensure last tile landed
    }
    BAR();
  }

  // ---- epilogue: wave owns 128x64; C row = quad*4+reg, col = l16 ----
  const size_t cr0 = m0 + wr * 128 + quad * 4;
  const size_t cc0 = n0 + wc * 64 + l16;
#pragma unroll
  for (int m = 0; m < 8; ++m) {
    const size_t rb = cr0 + m * 16;
#pragma unroll
    for (int n = 0; n < 4; ++n) {
      const size_t cb = cc0 + n * 16;
#pragma unroll
      for (int rr = 0; rr < 4; ++rr) {
        float x = acc[m][n][rr];
        if (MODE == 0) x = x > 0.f ? x : 0.2f * x;
        C[(rb + rr) * N + cb] = (f16)x;
      }
    }
  }
}

// ---- fused attention core: T=F.H2^T (MFMA), softmax(T@adjT), An=P@F+F,
// ---- LN -> An (overwrites H2 buffer, block-local), row-mean -> Msh fp16.
#define HP2 1032
__global__ __launch_bounds__(256, 4) void fused_attn(
    const float* __restrict__ F, const float* __restrict__ adj,
    f16* __restrict__ H2,  // in: H2, out: An (same region, per-batch)
    const float* __restrict__ lnw, const float* __restrict__ lnb,
    f16* __restrict__ Msh) {
  __shared__ __align__(16) f16 Hs[18 * HP2];  // 36.3 KB: H2 tile
  __shared__ float Ts[18 * 20];               // T, then attn P (pitch 20)
  __shared__ float Red[324];                  // adj; later LN reduce scratch

  const int tid = threadIdx.x;
  const int lane = tid & 63, wave = tid >> 6;
  const int quad = lane >> 4, l16 = lane & 15;
  const int b = blockIdx.x;
  const float* Fb = F + (size_t)b * 18432;
  f16* Hb = H2 + (size_t)b * 18432;

  for (int i = tid; i < 2304; i += 256) {  // stage H2 (half8 coalesced)
    const int r = i >> 7, g = i & 127;
    *(half8*)(Hs + r * HP2 + g * 8) = *(const half8*)(Hb + r * 1024 + g * 8);
  }
  for (int i = tid; i < 324; i += 256) Red[i] = adj[i];
  __syncthreads();

  // T[m][n] = sum_k F[m,k]*H2[n,k] via MFMA; wave owns tile (mt,nt)
  {
    const int mt = wave >> 1, nt = wave & 1;
    const int arow = min(mt * 16 + l16, 17);
    const int brow = min(nt * 16 + l16, 17);
    const float* ap = Fb + arow * 1024 + quad * 8;
    const f16* bp = Hs + brow * HP2 + quad * 8;
    floatx4 acc = (floatx4){0.f, 0.f, 0.f, 0.f};
    for (int kc = 0; kc < 1024; kc += 32) {
      floatx4 a0 = *(const floatx4*)(ap + kc);
      floatx4 a1 = *(const floatx4*)(ap + kc + 4);
      half8 af;
      af[0] = (f16)a0[0]; af[1] = (f16)a0[1]; af[2] = (f16)a0[2]; af[3] = (f16)a0[3];
      af[4] = (f16)a1[0]; af[5] = (f16)a1[1]; af[6] = (f16)a1[2]; af[7] = (f16)a1[3];
      half8 bf = *(const half8*)(bp + kc);
      acc = __builtin_amdgcn_mfma_f32_16x16x32_f16(af, bf, acc, 0, 0, 0);
    }
    const int row = mt * 16 + quad * 4, col = nt * 16 + l16;
    if (col < 18) {
#pragma unroll
      for (int r = 0; r < 4; ++r)
        if (row + r < 18) Ts[(row + r) * 20 + col] = acc[r];
    }
  }
  __syncthreads();

  // S = T @ adj^T, row softmax -> P (in-place in Ts); lanes 0..17
  if (tid < 18) {
    float t[18], s[18];
#pragma unroll
    for (int j = 0; j < 18; ++j) t[j] = Ts[tid * 20 + j];
    float mx = -3.4e38f;
    for (int m = 0; m < 18; ++m) {
      float a = 0.f;
#pragma unroll
      for (int j = 0; j < 18; ++j) a += t[j] * Red[m * 18 + j];
      s[m] = a; mx = fmaxf(mx, a);
    }
    float sum = 0.f;
    for (int m = 0; m < 18; ++m) { s[m] = __expf(s[m] - mx); sum += s[m]; }
    const float inv = 1.f / sum;
    for (int m = 0; m < 18; ++m) Ts[tid * 20 + m] = s[m] * inv;
  }
  __syncthreads();

  // An = P@F + F, thread-per-column (cols d0+256k), fp32 F from global
  const int d0 = tid;
  floatx4 an[18];
#pragma unroll
  for (int i = 0; i < 18; ++i) an[i] = (floatx4){0.f, 0.f, 0.f, 0.f};
#pragma unroll
  for (int jb = 0; jb < 5; ++jb) {
    const int jn = (jb < 4) ? 4 : 2;
    floatx4 fj[4];
#pragma unroll
    for (int jj = 0; jj < 4; ++jj) {
      if (jj < jn) {
        const float* fp = Fb + (jb * 4 + jj) * 1024 + d0;
        fj[jj] = (floatx4){fp[0], fp[256], fp[512], fp[768]};
        an[jb * 4 + jj] += fj[jj];  // +F residual goes to row j
      }
    }
#pragma unroll
    for (int i = 0; i < 18; ++i) {
      floatx4 p4 = *(const floatx4*)(Ts + i * 20 + jb * 4);
#pragma unroll
      for (int jj = 0; jj < 4; ++jj)
        if (jj < jn) an[i] += p4[jj] * fj[jj];
    }
  }
  // stash An to Hs (fp16) + per-thread LN partials
  float s[18], ss[18];
#pragma unroll
  for (int i = 0; i < 18; ++i) {
    Hs[i * HP2 + d0] = (f16)an[i][0];
    Hs[i * HP2 + d0 + 256] = (f16)an[i][1];
    Hs[i * HP2 + d0 + 512] = (f16)an[i][2];
    Hs[i * HP2 + d0 + 768] = (f16)an[i][3];
    s[i] = an[i][0] + an[i][1] + an[i][2] + an[i][3];
    ss[i] = an[i][0] * an[i][0] + an[i][1] * an[i][1] +
            an[i][2] * an[i][2] + an[i][3] * an[i][3];
  }
#pragma unroll
  for (int i = 0; i < 18; ++i) {
#pragma unroll
    for (int off = 32; off > 0; off >>= 1) {
      s[i] += __shfl_xor(s[i], off);
      ss[i] += __shfl_xor(ss[i], off);
    }
  }
  if (lane == 0) {
#pragma unroll
    for (int i = 0; i < 18; ++i) {
      Red[wave * 36 + i] = s[i];
      Red[wave * 36 + 18 + i] = ss[i];
    }
  }
  __syncthreads();
  if (tid < 18) {
    const float sv = Red[tid] + Red[36 + tid] + Red[72 + tid] + Red[108 + tid];
    const float sq = Red[18 + tid] + Red[54 + tid] + Red[90 + tid] + Red[126 + tid];
    const float mu = sv * (1.f / 1024.f);
    Red[144 + tid] = mu;
    Red[162 + tid] = rsqrtf(sq * (1.f / 1024.f) - mu * mu + 1e-5f);
  }
  __syncthreads();

  // normalize, write An (=Hb) fp16 + Msh row-mean fp16
  const floatx4 wv = (floatx4){lnw[d0], lnw[d0 + 256], lnw[d0 + 512], lnw[d0 + 768]};
  const floatx4 bv = (floatx4){lnb[d0], lnb[d0 + 256], lnb[d0 + 512], lnb[d0 + 768]};
  floatx4 msum = (floatx4){0.f, 0.f, 0.f, 0.f};
#pragma unroll
  for (int i = 0; i < 18; ++i) {
    const float mu = Red[144 + i], rs = Red[162 + i];
    floatx4 v = (floatx4){(float)Hs[i * HP2 + d0], (float)Hs[i * HP2 + d0 + 256],
                          (float)Hs[i * HP2 + d0 + 512], (float)Hs[i * HP2 + d0 + 768]};
    floatx4 o;
#pragma unroll
    for (int k = 0; k < 4; ++k) o[k] = (v[k] - mu) * rs * wv[k] + bv[k];
    msum += o;
    Hb[i * 1024 + d0] = (f16)o[0];
    Hb[i * 1024 + d0 + 256] = (f16)o[1];
    Hb[i * 1024 + d0 + 512] = (f16)o[2];
    Hb[i * 1024 + d0 + 768] = (f16)o[3];
  }
  f16* mp = Msh + (size_t)b * 1024;
  mp[d0] = (f16)(msum[0] * (1.f / 18.f));
  mp[d0 + 256] = (f16)(msum[1] * (1.f / 18.f));
  mp[d0 + 512] = (f16)(msum[2] * (1.f / 18.f));
  mp[d0 + 768] = (f16)(msum[3] * (1.f / 18.f));
}

// ---- head GEMM: out[M x 14] = A[M x 1024](f16) @ W[14 x 1024]^T + bias ----
// grid.x = M/128; W staged fp16 in LDS; MFMA 16x16x32.
__global__ __launch_bounds__(256, 4) void head_gemm(
    const f16* __restrict__ A, const float* __restrict__ W,
    const float* __restrict__ bias, float* __restrict__ out) {
  __shared__ __align__(16) f16 Ws[14 * 1032];
  const int tid = threadIdx.x, lane = tid & 63, wave = tid >> 6;
  const int quad = lane >> 4, l16 = lane & 15;
  for (int i = tid; i < 3584; i += 256) {  // 14 rows x 256 float4 groups
    const int r = i >> 8, g = i & 255;
    floatx4 v = *(const floatx4*)(W + r * 1024 + g * 4);
    half4 h;
#pragma unroll
    for (int t = 0; t < 4; ++t) h[t] = (f16)v[t];
    *(half4*)(Ws + r * 1032 + g * 4) = h;
  }
  __syncthreads();
  const f16* bp = Ws + min(l16, 13) * 1032 + quad * 8;
  const float bia = (l16 < 14) ? bias[l16] : 0.f;
  const size_t mbase = (size_t)blockIdx.x * 128 + wave * 32;
#pragma unroll
  for (int mt = 0; mt < 2; ++mt) {
    const size_t m0 = mbase + mt * 16;
    const f16* apx = A + (m0 + l16) * 1024 + quad * 8;
    floatx4 acc = (floatx4){0.f, 0.f, 0.f, 0.f};
    for (int kc = 0; kc < 1024; kc += 32) {
      half8 af = *(const half8*)(apx + kc);
      half8 bf = *(const half8*)(bp + kc);
      acc = __builtin_amdgcn_mfma_f32_16x16x32_f16(af, bf, acc, 0, 0, 0);
    }
    if (l16 < 14) {
      const size_t row = m0 + quad * 4;
#pragma unroll
      for (int r = 0; r < 4; ++r) out[(row + r) * 14 + l16] = acc[r] + bia;
    }
  }
}

extern "C" void kernel_launch(void* const* d_in, const int* in_sizes, int n_in,
                              void* d_out, int out_size, void* d_ws, size_t ws_size,
                              hipStream_t stream) {
  const float* F    = (const float*)d_in[0];
  const float* adj  = (const float*)d_in[1];
  const float* w1   = (const float*)d_in[2];
  const float* w2   = (const float*)d_in[3];
  const float* lnw  = (const float*)d_in[4];
  const float* lnb  = (const float*)d_in[5];
  const float* fcnw = (const float*)d_in[6];
  const float* fcnb = (const float*)d_in[7];
  const float* fcgw = (const float*)d_in[8];
  const float* fcgb = (const float*)d_in[9];

  float* out_node  = (float*)d_out;
  float* out_graph = out_node + (size_t)2048 * 18 * 14;

  char* ws = (char*)d_ws;
  f16* W2t = (f16*)ws;                        // 4 MiB
  f16* W1t = (f16*)(ws + (size_t)(4 << 20));  // 4 MiB
  char* p8 = ws + (size_t)(8 << 20);

  transpose_w<<<dim3(64, 32), dim3(32, 8), 0, stream>>>(w1, W1t, 1024, 2048);
  transpose_w<<<dim3(32, 64), dim3(32, 8), 0, stream>>>(w2, W2t, 2048, 1024);

  const size_t G1_FULL = 75497472ull;   // 36864*1024*2
  const size_t X1_FULL = 150994944ull;  // 36864*2048*2
  const size_t NEED_A = (size_t)(8 << 20) + G1_FULL + X1_FULL;
  const size_t NEED_B = (size_t)(8 << 20) + G1_FULL + 9437184ull + 18874368ull + 4194304ull;

  if (ws_size >= NEED_A) {
    // Plan A: full batch. H2/An alias G1; Msh aliases X1 (dead after GEMM2).
    f16* G1 = (f16*)p8;
    f16* H2 = (f16*)p8;
    f16* X1 = (f16*)(p8 + G1_FULL);
    f16* Msh = (f16*)(p8 + G1_FULL);  // X1 region, reused after GEMM2
    adjmix<<<dim3(2048), 256, 0, stream>>>(F, adj, G1);
    gemm8<0><<<dim3(1152), 512, 0, stream>>>(G1, W1t, X1, 36864, 2048, 1024);
    gemm8<1><<<dim3(576), 512, 0, stream>>>(X1, W2t, H2, 36864, 1024, 2048);
    fused_attn<<<2048, 256, 0, stream>>>(F, adj, H2, lnw, lnb, Msh);
    head_gemm<<<288, 256, 0, stream>>>(H2, fcnw, fcnb, out_node);
    head_gemm<<<16, 256, 0, stream>>>(Msh, fcgw, fcgb, out_graph);
  } else if (ws_size >= NEED_B) {
    // Plan B: chunked GEMMs, full H2/An + Msh.
    const int CH = 256, MC = CH * 18;
    f16* H2 = (f16*)p8;
    f16* G1c = (f16*)(p8 + G1_FULL);
    f16* X1c = (f16*)(p8 + G1_FULL + 9437184ull);
    f16* Msh = (f16*)(p8 + G1_FULL + 9437184ull + 18874368ull);
    for (int c = 0; c < 8; ++c) {
      const float* Fc = F + (size_t)c * CH * 18432;
      adjmix<<<dim3(CH), 256, 0, stream>>>(Fc, adj, G1c);
      gemm8<0><<<dim3(144), 512, 0, stream>>>(G1c, W1t, X1c, MC, 2048, 1024);
      gemm8<1><<<dim3(72), 512, 0, stream>>>(X1c, W2t,
                                             H2 + (size_t)c * MC * 1024,
                                             MC, 1024, 2048);
    }
    fused_attn<<<2048, 256, 0, stream>>>(F, adj, H2, lnw, lnb, Msh);
    head_gemm<<<288, 256, 0, stream>>>(H2, fcnw, fcnb, out_node);
    head_gemm<<<16, 256, 0, stream>>>(Msh, fcgw, fcgb, out_graph);
  } else {
    // Plan C: fully chunked (~46.7 MB floor).
    const int CH = 256, MC = CH * 18;
    f16* G1c = (f16*)p8;
    f16* X1c = (f16*)(p8 + 9437184ull);
    f16* H2c = (f16*)(p8 + 9437184ull + 18874368ull);
    f16* Mshc = (f16*)(p8 + 9437184ull + 18874368ull + 9437184ull);
    for (int c = 0; c < 8; ++c) {
      const float* Fc = F + (size_t)c * CH * 18432;
      adjmix<<<dim3(CH), 256, 0, stream>>>(Fc, adj, G1c);
      gemm8<0><<<dim3(144), 512, 0, stream>>>(G1c, W1t, X1c, MC, 2048, 1024);
      gemm8<1><<<dim3(72), 512, 0, stream>>>(X1c, W2t, H2c, MC, 1024, 2048);
      fused_attn<<<CH, 256, 0, stream>>>(Fc, adj, H2c, lnw, lnb, Mshc);
      head_gemm<<<36, 256, 0, stream>>>(H2c, fcnw, fcnb, out_node + (size_t)c * CH * 252);
      head_gemm<<<2, 256, 0, stream>>>(Mshc, fcgw, fcgb, out_graph + (size_t)c * CH * 14);
    }
  }
}

// Round 7
// 757.572 us; speedup vs baseline: 1.4735x; 1.0163x over previous
//
#include <hip/hip_runtime.h>

typedef unsigned int u32;
typedef _Float16 f16;
typedef __attribute__((ext_vector_type(8))) _Float16 half8;
typedef __attribute__((ext_vector_type(4))) _Float16 half4;
typedef __attribute__((ext_vector_type(4))) float floatx4;

// ------------- transpose + fp32->fp16: out[C][R] = (f16)in[R][C]^T -------
__global__ void transpose_w(const float* __restrict__ in, f16* __restrict__ out,
                            int R, int C) {
  __shared__ f16 t[32][33];
  const int bx = blockIdx.x * 32, by = blockIdx.y * 32;
  const int x = threadIdx.x, y0 = threadIdx.y;
  for (int y = y0; y < 32; y += 8)
    t[y][x] = (f16)in[(size_t)(by + y) * C + bx + x];
  __syncthreads();
  for (int y = y0; y < 32; y += 8)
    out[(size_t)(bx + y) * R + by + x] = t[x][y];
}

// ---- G1[b] = adj @ F[b] (18x18 @ 18x1024), fp16 out. One block/batch, ----
// ---- float4 loads + half4 stores (G13). ----
__global__ __launch_bounds__(256) void adjmix(const float* __restrict__ F,
                                              const float* __restrict__ adj,
                                              f16* __restrict__ G1) {
  __shared__ float adjs[324];
  for (int i = threadIdx.x; i < 324; i += 256) adjs[i] = adj[i];
  __syncthreads();
  const int d = threadIdx.x * 4;
  const size_t base = (size_t)blockIdx.x * 18432;
  floatx4 f[18];
#pragma unroll
  for (int j = 0; j < 18; ++j)
    f[j] = *(const floatx4*)(F + base + j * 1024 + d);
#pragma unroll
  for (int i = 0; i < 18; ++i) {
    floatx4 a = (floatx4){0.f, 0.f, 0.f, 0.f};
#pragma unroll
    for (int j = 0; j < 18; ++j) a += adjs[i * 18 + j] * f[j];
    half4 h;
#pragma unroll
    for (int k = 0; k < 4; ++k) h[k] = (f16)a[k];
    *(half4*)(G1 + base + i * 1024 + d) = h;
  }
}

// ---- C = A[M,K] @ Bt[N,K]^T, fp16 MFMA, 128x128 tile, BK=64, 4 waves. ----
// ---- m97/m103 structure (912 TF measured on gfx950): single-buffer 32KB
// ---- LDS, 2 barriers/K-tile, compiler-scheduled waits, ~3 blocks/CU for
// ---- cross-BLOCK latency hiding (beats 1-block/CU intra-block pipelining:
// ---- 256^2 R1 measured 715 TF in-round). + T2 swizzle (R1-verified mech:
// ---- pre-swizzled global source, XOR on ds_read) -> 0 bank conflicts.
// ---- + chunked-XCD swizzle, nt-INNER order: consecutive blocks share the
// ---- A-strip (A fetched ~once), 4MB B panel stays L2-hot.
template <int MODE>
__global__ __launch_bounds__(256) void gemm128(const f16* __restrict__ A,
                                               const f16* __restrict__ Bt,
                                               f16* __restrict__ C,
                                               int M, int N, int K) {
  __shared__ __align__(16) f16 As[8192];
  __shared__ __align__(16) f16 Bs[8192];
  const int tid = threadIdx.x;
  const int wave = tid >> 6, lane = tid & 63;
  const int l16 = lane & 15, quad = lane >> 4;
  const int wr = wave >> 1, wc = wave & 1;  // 2M x 2N waves, 64x64 each

  // ---- chunked XCD swizzle (bijective), nt-inner tile order ----
  const int NT = N >> 7, MT = M >> 7;
  (void)MT;
  const int nwg = gridDim.x;
  const int orig = blockIdx.x;
  const int q = nwg >> 3, r = nwg & 7;
  const int xcd = orig & 7, idx = orig >> 3;
  const int wg = (xcd < r) ? xcd * (q + 1) + idx : r * (q + 1) + (xcd - r) * q + idx;
  const int nt = wg % NT, mt = wg / NT;
  const size_t m0 = (size_t)mt << 7, n0 = (size_t)nt << 7;

  // ---- staging: 4 gloads/matrix; pre-swizzled source (rule 21) ----
  // LDS linear slot (row, cc) holds global chunk (row, cc ^ (row&7)).
  const f16* gA[4];
  const f16* gB[4];
  int ldso[4];
#pragma unroll
  for (int g = 0; g < 4; ++g) {
    const int c = g * 256 + tid;     // chunk 0..1023; row = c/8 (0..127)
    const int row = c >> 3;
    const int cc = (c & 7) ^ (row & 7);
    gA[g] = A + (m0 + row) * (size_t)K + cc * 8;
    gB[g] = Bt + (n0 + row) * (size_t)K + cc * 8;
    ldso[g] = (g * 256 + (tid & ~63)) * 8;  // wave-uniform base (halfs)
  }

  // ---- T2 read-side swizzle (half units; XOR bits 3..5) ----
  const int axor = (l16 & 7) << 3;
  const int abase = (wr * 64 + l16) * 64 + quad * 8;
  const int bbase = (wc * 64 + l16) * 64 + quad * 8;

  floatx4 acc[4][4];
#pragma unroll
  for (int i = 0; i < 4; ++i)
#pragma unroll
    for (int j = 0; j < 4; ++j) acc[i][j] = (floatx4){0.f, 0.f, 0.f, 0.f};

  const int KT = K >> 6;
  for (int T = 0; T < KT; ++T) {
    const int kk = T * 64;
#pragma unroll
    for (int g = 0; g < 4; ++g)
      __builtin_amdgcn_global_load_lds(
          (const __attribute__((address_space(1))) void*)(gA[g] + kk),
          (__attribute__((address_space(3))) void*)(As + ldso[g]), 16, 0, 0);
#pragma unroll
    for (int g = 0; g < 4; ++g)
      __builtin_amdgcn_global_load_lds(
          (const __attribute__((address_space(1))) void*)(gB[g] + kk),
          (__attribute__((address_space(3))) void*)(Bs + ldso[g]), 16, 0, 0);
    __syncthreads();  // drains vmcnt+lgkm (compiler-emitted) -> tile ready
#pragma unroll
    for (int s = 0; s < 2; ++s) {
      half8 a[4], b[4];
#pragma unroll
      for (int i = 0; i < 4; ++i)
        a[i] = *(const half8*)(As + ((abase + i * 1024 + s * 32) ^ axor));
#pragma unroll
      for (int j = 0; j < 4; ++j)
        b[j] = *(const half8*)(Bs + ((bbase + j * 1024 + s * 32) ^ axor));
#pragma unroll
      for (int i = 0; i < 4; ++i)
#pragma unroll
        for (int j = 0; j < 4; ++j)
          acc[i][j] = __builtin_amdgcn_mfma_f32_16x16x32_f16(a[i], b[j], acc[i][j], 0, 0, 0);
    }
    __syncthreads();  // all reads consumed before next stage overwrites
  }

  // ---- epilogue: wave owns 64x64; C row = quad*4+reg, col = l16 ----
  const size_t cr0 = m0 + wr * 64 + quad * 4;
  const size_t cc0 = n0 + wc * 64 + l16;
#pragma unroll
  for (int i = 0; i < 4; ++i) {
    const size_t rb = cr0 + i * 16;
#pragma unroll
    for (int j = 0; j < 4; ++j) {
      const size_t cb = cc0 + j * 16;
#pragma unroll
      for (int rr = 0; rr < 4; ++rr) {
        float x = acc[i][j][rr];
        if (MODE == 0) x = x > 0.f ? x : 0.2f * x;
        C[(rb + rr) * N + cb] = (f16)x;
      }
    }
  }
}

// ---- fused attention core: T=F.H2^T (MFMA), softmax(T@adjT), An=P@F+F,
// ---- LN -> An (overwrites H2 buffer, block-local), row-mean -> Msh fp16.
#define HP2 1032
__global__ __launch_bounds__(256, 4) void fused_attn(
    const float* __restrict__ F, const float* __restrict__ adj,
    f16* __restrict__ H2,  // in: H2, out: An (same region, per-batch)
    const float* __restrict__ lnw, const float* __restrict__ lnb,
    f16* __restrict__ Msh) {
  __shared__ __align__(16) f16 Hs[18 * HP2];  // 36.3 KB: H2 tile
  __shared__ float Ts[18 * 20];               // T, then attn P (pitch 20)
  __shared__ float Red[324];                  // adj; later LN reduce scratch

  const int tid = threadIdx.x;
  const int lane = tid & 63, wave = tid >> 6;
  const int quad = lane >> 4, l16 = lane & 15;
  const int b = blockIdx.x;
  const float* Fb = F + (size_t)b * 18432;
  f16* Hb = H2 + (size_t)b * 18432;

  for (int i = tid; i < 2304; i += 256) {  // stage H2 (half8 coalesced)
    const int r = i >> 7, g = i & 127;
    *(half8*)(Hs + r * HP2 + g * 8) = *(const half8*)(Hb + r * 1024 + g * 8);
  }
  for (int i = tid; i < 324; i += 256) Red[i] = adj[i];
  __syncthreads();

  // T[m][n] = sum_k F[m,k]*H2[n,k] via MFMA; wave owns tile (mt,nt)
  {
    const int mt = wave >> 1, nt = wave & 1;
    const int arow = min(mt * 16 + l16, 17);
    const int brow = min(nt * 16 + l16, 17);
    const float* ap = Fb + arow * 1024 + quad * 8;
    const f16* bp = Hs + brow * HP2 + quad * 8;
    floatx4 acc = (floatx4){0.f, 0.f, 0.f, 0.f};
    for (int kc = 0; kc < 1024; kc += 32) {
      floatx4 a0 = *(const floatx4*)(ap + kc);
      floatx4 a1 = *(const floatx4*)(ap + kc + 4);
      half8 af;
      af[0] = (f16)a0[0]; af[1] = (f16)a0[1]; af[2] = (f16)a0[2]; af[3] = (f16)a0[3];
      af[4] = (f16)a1[0]; af[5] = (f16)a1[1]; af[6] = (f16)a1[2]; af[7] = (f16)a1[3];
      half8 bf = *(const half8*)(bp + kc);
      acc = __builtin_amdgcn_mfma_f32_16x16x32_f16(af, bf, acc, 0, 0, 0);
    }
    const int row = mt * 16 + quad * 4, col = nt * 16 + l16;
    if (col < 18) {
#pragma unroll
      for (int r = 0; r < 4; ++r)
        if (row + r < 18) Ts[(row + r) * 20 + col] = acc[r];
    }
  }
  __syncthreads();

  // S = T @ adj^T, row softmax -> P (in-place in Ts); lanes 0..17
  if (tid < 18) {
    float t[18], s[18];
#pragma unroll
    for (int j = 0; j < 18; ++j) t[j] = Ts[tid * 20 + j];
    float mx = -3.4e38f;
    for (int m = 0; m < 18; ++m) {
      float a = 0.f;
#pragma unroll
      for (int j = 0; j < 18; ++j) a += t[j] * Red[m * 18 + j];
      s[m] = a; mx = fmaxf(mx, a);
    }
    float sum = 0.f;
    for (int m = 0; m < 18; ++m) { s[m] = __expf(s[m] - mx); sum += s[m]; }
    const float inv = 1.f / sum;
    for (int m = 0; m < 18; ++m) Ts[tid * 20 + m] = s[m] * inv;
  }
  __syncthreads();

  // An = P@F + F, thread-per-column (cols d0+256k), fp32 F from global
  const int d0 = tid;
  floatx4 an[18];
#pragma unroll
  for (int i = 0; i < 18; ++i) an[i] = (floatx4){0.f, 0.f, 0.f, 0.f};
#pragma unroll
  for (int jb = 0; jb < 5; ++jb) {
    const int jn = (jb < 4) ? 4 : 2;
    floatx4 fj[4];
#pragma unroll
    for (int jj = 0; jj < 4; ++jj) {
      if (jj < jn) {
        const float* fp = Fb + (jb * 4 + jj) * 1024 + d0;
        fj[jj] = (floatx4){fp[0], fp[256], fp[512], fp[768]};
        an[jb * 4 + jj] += fj[jj];  // +F residual goes to row j
      }
    }
#pragma unroll
    for (int i = 0; i < 18; ++i) {
      floatx4 p4 = *(const floatx4*)(Ts + i * 20 + jb * 4);
#pragma unroll
      for (int jj = 0; jj < 4; ++jj)
        if (jj < jn) an[i] += p4[jj] * fj[jj];
    }
  }
  // stash An to Hs (fp16) + per-thread LN partials
  float s[18], ss[18];
#pragma unroll
  for (int i = 0; i < 18; ++i) {
    Hs[i * HP2 + d0] = (f16)an[i][0];
    Hs[i * HP2 + d0 + 256] = (f16)an[i][1];
    Hs[i * HP2 + d0 + 512] = (f16)an[i][2];
    Hs[i * HP2 + d0 + 768] = (f16)an[i][3];
    s[i] = an[i][0] + an[i][1] + an[i][2] + an[i][3];
    ss[i] = an[i][0] * an[i][0] + an[i][1] * an[i][1] +
            an[i][2] * an[i][2] + an[i][3] * an[i][3];
  }
#pragma unroll
  for (int i = 0; i < 18; ++i) {
#pragma unroll
    for (int off = 32; off > 0; off >>= 1) {
      s[i] += __shfl_xor(s[i], off);
      ss[i] += __shfl_xor(ss[i], off);
    }
  }
  if (lane == 0) {
#pragma unroll
    for (int i = 0; i < 18; ++i) {
      Red[wave * 36 + i] = s[i];
      Red[wave * 36 + 18 + i] = ss[i];
    }
  }
  __syncthreads();
  if (tid < 18) {
    const float sv = Red[tid] + Red[36 + tid] + Red[72 + tid] + Red[108 + tid];
    const float sq = Red[18 + tid] + Red[54 + tid] + Red[90 + tid] + Red[126 + tid];
    const float mu = sv * (1.f / 1024.f);
    Red[144 + tid] = mu;
    Red[162 + tid] = rsqrtf(sq * (1.f / 1024.f) - mu * mu + 1e-5f);
  }
  __syncthreads();

  // normalize, write An (=Hb) fp16 + Msh row-mean fp16
  const floatx4 wv = (floatx4){lnw[d0], lnw[d0 + 256], lnw[d0 + 512], lnw[d0 + 768]};
  const floatx4 bv = (floatx4){lnb[d0], lnb[d0 + 256], lnb[d0 + 512], lnb[d0 + 768]};
  floatx4 msum = (floatx4){0.f, 0.f, 0.f, 0.f};
#pragma unroll
  for (int i = 0; i < 18; ++i) {
    const float mu = Red[144 + i], rs = Red[162 + i];
    floatx4 v = (floatx4){(float)Hs[i * HP2 + d0], (float)Hs[i * HP2 + d0 + 256],
                          (float)Hs[i * HP2 + d0 + 512], (float)Hs[i * HP2 + d0 + 768]};
    floatx4 o;
#pragma unroll
    for (int k = 0; k < 4; ++k) o[k] = (v[k] - mu) * rs * wv[k] + bv[k];
    msum += o;
    Hb[i * 1024 + d0] = (f16)o[0];
    Hb[i * 1024 + d0 + 256] = (f16)o[1];
    Hb[i * 1024 + d0 + 512] = (f16)o[2];
    Hb[i * 1024 + d0 + 768] = (f16)o[3];
  }
  f16* mp = Msh + (size_t)b * 1024;
  mp[d0] = (f16)(msum[0] * (1.f / 18.f));
  mp[d0 + 256] = (f16)(msum[1] * (1.f / 18.f));
  mp[d0 + 512] = (f16)(msum[2] * (1.f / 18.f));
  mp[d0 + 768] = (f16)(msum[3] * (1.f / 18.f));
}

// ---- head GEMM: out[M x 14] = A[M x 1024](f16) @ W[14 x 1024]^T + bias ----
// grid.x = M/128; W staged fp16 in LDS; MFMA 16x16x32.
__global__ __launch_bounds__(256, 4) void head_gemm(
    const f16* __restrict__ A, const float* __restrict__ W,
    const float* __restrict__ bias, float* __restrict__ out) {
  __shared__ __align__(16) f16 Ws[14 * 1032];
  const int tid = threadIdx.x, lane = tid & 63, wave = tid >> 6;
  const int quad = lane >> 4, l16 = lane & 15;
  for (int i = tid; i < 3584; i += 256) {  // 14 rows x 256 float4 groups
    const int r = i >> 8, g = i & 255;
    floatx4 v = *(const floatx4*)(W + r * 1024 + g * 4);
    half4 h;
#pragma unroll
    for (int t = 0; t < 4; ++t) h[t] = (f16)v[t];
    *(half4*)(Ws + r * 1032 + g * 4) = h;
  }
  __syncthreads();
  const f16* bp = Ws + min(l16, 13) * 1032 + quad * 8;
  const float bia = (l16 < 14) ? bias[l16] : 0.f;
  const size_t mbase = (size_t)blockIdx.x * 128 + wave * 32;
#pragma unroll
  for (int mt = 0; mt < 2; ++mt) {
    const size_t m0 = mbase + mt * 16;
    const f16* apx = A + (m0 + l16) * 1024 + quad * 8;
    floatx4 acc = (floatx4){0.f, 0.f, 0.f, 0.f};
    for (int kc = 0; kc < 1024; kc += 32) {
      half8 af = *(const half8*)(apx + kc);
      half8 bf = *(const half8*)(bp + kc);
      acc = __builtin_amdgcn_mfma_f32_16x16x32_f16(af, bf, acc, 0, 0, 0);
    }
    if (l16 < 14) {
      const size_t row = m0 + quad * 4;
#pragma unroll
      for (int r = 0; r < 4; ++r) out[(row + r) * 14 + l16] = acc[r] + bia;
    }
  }
}

extern "C" void kernel_launch(void* const* d_in, const int* in_sizes, int n_in,
                              void* d_out, int out_size, void* d_ws, size_t ws_size,
                              hipStream_t stream) {
  const float* F    = (const float*)d_in[0];
  const float* adj  = (const float*)d_in[1];
  const float* w1   = (const float*)d_in[2];
  const float* w2   = (const float*)d_in[3];
  const float* lnw  = (const float*)d_in[4];
  const float* lnb  = (const float*)d_in[5];
  const float* fcnw = (const float*)d_in[6];
  const float* fcnb = (const float*)d_in[7];
  const float* fcgw = (const float*)d_in[8];
  const float* fcgb = (const float*)d_in[9];

  float* out_node  = (float*)d_out;
  float* out_graph = out_node + (size_t)2048 * 18 * 14;

  char* ws = (char*)d_ws;
  f16* W2t = (f16*)ws;                        // 4 MiB
  f16* W1t = (f16*)(ws + (size_t)(4 << 20));  // 4 MiB
  char* p8 = ws + (size_t)(8 << 20);

  transpose_w<<<dim3(64, 32), dim3(32, 8), 0, stream>>>(w1, W1t, 1024, 2048);
  transpose_w<<<dim3(32, 64), dim3(32, 8), 0, stream>>>(w2, W2t, 2048, 1024);

  const size_t G1_FULL = 75497472ull;   // 36864*1024*2
  const size_t X1_FULL = 150994944ull;  // 36864*2048*2
  const size_t NEED_A = (size_t)(8 << 20) + G1_FULL + X1_FULL;
  const size_t NEED_B = (size_t)(8 << 20) + G1_FULL + 9437184ull + 18874368ull + 4194304ull;

  if (ws_size >= NEED_A) {
    // Plan A: full batch. H2/An alias G1; Msh aliases X1 (dead after GEMM2).
    f16* G1 = (f16*)p8;
    f16* H2 = (f16*)p8;
    f16* X1 = (f16*)(p8 + G1_FULL);
    f16* Msh = (f16*)(p8 + G1_FULL);  // X1 region, reused after GEMM2
    adjmix<<<dim3(2048), 256, 0, stream>>>(F, adj, G1);
    gemm128<0><<<dim3(4608), 256, 0, stream>>>(G1, W1t, X1, 36864, 2048, 1024);
    gemm128<1><<<dim3(2304), 256, 0, stream>>>(X1, W2t, H2, 36864, 1024, 2048);
    fused_attn<<<2048, 256, 0, stream>>>(F, adj, H2, lnw, lnb, Msh);
    head_gemm<<<288, 256, 0, stream>>>(H2, fcnw, fcnb, out_node);
    head_gemm<<<16, 256, 0, stream>>>(Msh, fcgw, fcgb, out_graph);
  } else if (ws_size >= NEED_B) {
    // Plan B: chunked GEMMs, full H2/An + Msh.
    const int CH = 256, MC = CH * 18;
    f16* H2 = (f16*)p8;
    f16* G1c = (f16*)(p8 + G1_FULL);
    f16* X1c = (f16*)(p8 + G1_FULL + 9437184ull);
    f16* Msh = (f16*)(p8 + G1_FULL + 9437184ull + 18874368ull);
    for (int c = 0; c < 8; ++c) {
      const float* Fc = F + (size_t)c * CH * 18432;
      adjmix<<<dim3(CH), 256, 0, stream>>>(Fc, adj, G1c);
      gemm128<0><<<dim3(576), 256, 0, stream>>>(G1c, W1t, X1c, MC, 2048, 1024);
      gemm128<1><<<dim3(288), 256, 0, stream>>>(X1c, W2t,
                                                H2 + (size_t)c * MC * 1024,
                                                MC, 1024, 2048);
    }
    fused_attn<<<2048, 256, 0, stream>>>(F, adj, H2, lnw, lnb, Msh);
    head_gemm<<<288, 256, 0, stream>>>(H2, fcnw, fcnb, out_node);
    head_gemm<<<16, 256, 0, stream>>>(Msh, fcgw, fcgb, out_graph);
  } else {
    // Plan C: fully chunked (~46.7 MB floor).
    const int CH = 256, MC = CH * 18;
    f16* G1c = (f16*)p8;
    f16* X1c = (f16*)(p8 + 9437184ull);
    f16* H2c = (f16*)(p8 + 9437184ull + 18874368ull);
    f16* Mshc = (f16*)(p8 + 9437184ull + 18874368ull + 9437184ull);
    for (int c = 0; c < 8; ++c) {
      const float* Fc = F + (size_t)c * CH * 18432;
      adjmix<<<dim3(CH), 256, 0, stream>>>(Fc, adj, G1c);
      gemm128<0><<<dim3(576), 256, 0, stream>>>(G1c, W1t, X1c, MC, 2048, 1024);
      gemm128<1><<<dim3(288), 256, 0, stream>>>(X1c, W2t, H2c, MC, 1024, 2048);
      fused_attn<<<CH, 256, 0, stream>>>(Fc, adj, H2c, lnw, lnb, Mshc);
      head_gemm<<<36, 256, 0, stream>>>(H2c, fcnw, fcnb, out_node + (size_t)c * CH * 252);
      head_gemm<<<2, 256, 0, stream>>>(Mshc, fcgw, fcgb, out_graph + (size_t)c * CH * 14);
    }
  }
}